// Round 2
// baseline (27750.620 us; speedup 1.0000x reference)
//
#include <hip/hip_runtime.h>
#include <math.h>

namespace {
constexpr int kB = 2, kS = 2048, kDH = 2048, kH = 16, kDN = 128, kDR = 64, kDV = 128;
constexpr int kKvLora = 512, kQLora = 1024, kHI = 8, kDI = 128, kTopK = 1024;
constexpr int kNTok = kB * kS;             // 4096
constexpr float kNeg = -1e30f;

// ---- workspace layout (float elements), ~170.4 MB total ----
constexpr size_t SC_WQA  = 0;        // 8*16   = 128
constexpr size_t SC_WQB  = 128;      // 24*8   = 192
constexpr size_t SC_WKVA = 320;      // 5*16   = 80
constexpr size_t SC_WKVB = 400;      // 32*4   = 128
constexpr size_t SC_WO   = 528;      // 16*16  = 256
constexpr size_t SC_HID  = 784;      // 4096*16 = 65536
constexpr size_t SC_CTX  = 66320;    // 4096*16 = 65536
constexpr size_t OFF_R1  = 132096;                     // qa(4.2M)/qi(4.2M)/ctx(8.4M)
constexpr size_t OFF_QBUF = OFF_R1 + 8388608;          // 12582912
constexpr size_t OFF_R2  = OFF_QBUF + 12582912;        // kva(2359296) then sel(131072 u32)
constexpr size_t OFF_R3  = OFF_R2 + 2359296;           // ckv(2097152) then ki(524288)+wgt(32768)
constexpr size_t OFF_KR  = OFF_R3 + 2097152;           // 262144
constexpr size_t OFF_KV  = OFF_KR + 262144;            // 16777216
constexpr size_t OFF_END = OFF_KV + 16777216;          // 42599424 floats
} // namespace

// Exact e4m3fn round-to-nearest-even quant-dequant for |x| <= 448 (incl. subnormals).
__device__ __forceinline__ float fp8_e4m3_qdq(float x) {
  float ax = fabsf(x);
  int e;
  (void)frexpf(ax, &e);          // ax = m * 2^e, m in [0.5,1)
  int ee = e - 1;                // floor(log2 ax)
  if (ee < -6) ee = -6;          // subnormal regime
  float q = ldexpf(1.0f, ee - 3);// quantization step (3 mantissa bits)
  float y = rintf(ax / q) * q;   // exact: q is a power of 2
  return (x < 0.0f) ? -y : y;
}

// scale = exp2(ceil(log2(amax/448))) computed exactly at the bit level
__device__ __forceinline__ float act_scale_from_amax(float amax) {
  float t = amax / 448.0f;
  unsigned u = __float_as_uint(t);
  int e = (int)((u >> 23) & 255u) - 127;
  if (u & 0x7fffffu) e += 1;
  return __uint_as_float((unsigned)(e + 127) << 23);
}

__device__ __forceinline__ float clamp448(float v) {
  return fminf(fmaxf(v, -448.0f), 448.0f);
}

__global__ __launch_bounds__(256) void fill_kernel(float* p, int n, float v) {
  int i = blockIdx.x * 256 + threadIdx.x;
  if (i < n) p[i] = v;
}

// ---------------- weight 128x128-block scale: Bsc[ob*KB+kb] = max(amax,1e-4)/448 ----------------
__global__ __launch_bounds__(256) void weight_scale_kernel(const float* __restrict__ W,
                                                           float* __restrict__ SC, int O, int I) {
  int kb = blockIdx.x, ob = blockIdx.y;
  int bo = ob * 128, bi = kb * 128;
  int tid = threadIdx.x;
  __shared__ float red[256];
  float am = 0.0f;
  for (int idx = tid; idx < 128 * 128; idx += 256) {
    int r = bo + (idx >> 7), c = bi + (idx & 127);
    if (r < O) am = fmaxf(am, fabsf(W[(size_t)r * I + c]));
  }
  red[tid] = am; __syncthreads();
  for (int s = 128; s >= 1; s >>= 1) {
    if (tid < s) red[tid] = fmaxf(red[tid], red[tid + s]);
    __syncthreads();
  }
  if (tid == 0) SC[(size_t)ob * gridDim.x + kb] = fmaxf(red[0], 1e-4f) / 448.0f;
}

// ---------------- activation per-(row,128-block) power-of-2 scale ----------------
__global__ __launch_bounds__(256) void act_scale_kernel(const float* __restrict__ X,
                                                        float* __restrict__ SC, int nblk) {
  int wid = blockIdx.x * 4 + (threadIdx.x >> 6);
  int lane = threadIdx.x & 63;
  if (wid >= nblk) return;
  const float* x = X + (size_t)wid * 128;
  float am = fmaxf(fabsf(x[lane]), fabsf(x[lane + 64]));
#pragma unroll
  for (int m = 32; m >= 1; m >>= 1) am = fmaxf(am, __shfl_xor(am, m, 64));
  if (lane == 0) SC[wid] = act_scale_from_amax(fmaxf(am, 1e-4f));
}

// ---------------- fused RMSNorm + activation qdq (per row) ----------------
__global__ __launch_bounds__(256) void rms_qdq_kernel(const float* __restrict__ X,
                                                      const float* __restrict__ G,
                                                      float* __restrict__ Y,
                                                      int C, int xs, int ys) {
  int row = blockIdx.x, tid = threadIdx.x;
  __shared__ float xr[1024];
  __shared__ float red[256];
  const float* x = X + (size_t)row * xs;
  float ssq = 0.0f;
  for (int i = tid; i < C; i += 256) { float v = x[i]; xr[i] = v; ssq += v * v; }
  red[tid] = ssq; __syncthreads();
  for (int s = 128; s >= 1; s >>= 1) { if (tid < s) red[tid] += red[tid + s]; __syncthreads(); }
  float inv = 1.0f / sqrtf(red[0] / (float)C + 1e-6f);
  __syncthreads();
  int wv = tid >> 6, lane = tid & 63;
  for (int blk = wv; blk < C / 128; blk += 4) {
    int i0 = blk * 128 + lane, i1 = i0 + 64;
    float y0 = xr[i0] * inv * G[i0];
    float y1 = xr[i1] * inv * G[i1];
    float am = fmaxf(fabsf(y0), fabsf(y1));
#pragma unroll
    for (int m = 32; m >= 1; m >>= 1) am = fmaxf(am, __shfl_xor(am, m, 64));
    am = fmaxf(am, 1e-4f);
    float scale = act_scale_from_amax(am);
    Y[(size_t)row * ys + i0] = fp8_e4m3_qdq(clamp448(y0 / scale)) * scale;
    Y[(size_t)row * ys + i1] = fp8_e4m3_qdq(clamp448(y1 / scale)) * scale;
  }
}

// ---------------- f32 GEMM with optional fused fp8 qdq on A and/or B ----------------
// C[m,n] = alpha * sum_k qdqA(A[m,k]) * qdqB(B[n,k]);  M fixed = kNTok
template <bool AQ, bool BQ>
__global__ __launch_bounds__(256) void gemm_kernel(const float* __restrict__ A,
                                                   const float* __restrict__ Asc,
                                                   const float* __restrict__ Bw,
                                                   const float* __restrict__ Bsc,
                                                   float* __restrict__ C,
                                                   int N, int K, float alpha) {
  __shared__ __align__(16) float As[16][68];
  __shared__ __align__(16) float Bs[16][68];
  int n0 = blockIdx.x * 64;
  int m0 = blockIdx.y * 64;
  int tid = threadIdx.x;
  int tx = tid & 15, ty = tid >> 4;
  int KB = K >> 7;
  float acc[4][4] = {};
  for (int k0 = 0; k0 < K; k0 += 16) {
    int kb = k0 >> 7;
#pragma unroll
    for (int t = 0; t < 4; ++t) {
      int idx = tid + t * 256;
      int rr = idx >> 4;   // 0..63
      int kk = idx & 15;
      float a = A[(size_t)(m0 + rr) * K + (k0 + kk)];
      if (AQ) {
        float s = Asc[(size_t)(m0 + rr) * KB + kb];
        a = fp8_e4m3_qdq(clamp448(a / s)) * s;
      }
      As[kk][rr] = a;
      float b = 0.0f;
      if (n0 + rr < N) {
        b = Bw[(size_t)(n0 + rr) * K + (k0 + kk)];
        if (BQ) {
          float s = Bsc[(size_t)((n0 + rr) >> 7) * KB + kb];
          b = fp8_e4m3_qdq(clamp448(b / s)) * s;
        }
      }
      Bs[kk][rr] = b;
    }
    __syncthreads();
#pragma unroll
    for (int kk = 0; kk < 16; ++kk) {
      float4 a = *(const float4*)&As[kk][ty * 4];
      float4 b = *(const float4*)&Bs[kk][tx * 4];
      float av[4] = {a.x, a.y, a.z, a.w};
      float bv[4] = {b.x, b.y, b.z, b.w};
#pragma unroll
      for (int i = 0; i < 4; ++i)
#pragma unroll
        for (int j = 0; j < 4; ++j) acc[i][j] += av[i] * bv[j];
    }
    __syncthreads();
  }
#pragma unroll
  for (int i = 0; i < 4; ++i) {
    int m = m0 + ty * 4 + i;
#pragma unroll
    for (int j = 0; j < 4; ++j) {
      int n = n0 + tx * 4 + j;
      if (n < N) C[(size_t)m * N + n] = alpha * acc[i][j];
    }
  }
}

// ---------------- RoPE: q (in place, per head) and k_rope -> KR ----------------
__global__ __launch_bounds__(64) void rope_kernel(float* __restrict__ Q,
                                                  const float* __restrict__ KVA,
                                                  float* __restrict__ KR,
                                                  const int* __restrict__ POS) {
  int t = blockIdx.x;  // b*S + s
  int tid = threadIdx.x;
  __shared__ float cs[32], sn[32];
  if (tid < 32) {
    int pos = POS[t];
    double inv = pow(10000.0, -((double)(2 * tid) / 64.0));
    float ang = (float)pos * (float)inv;
    cs[tid] = cosf(ang);
    sn[tid] = sinf(ang);
  }
  __syncthreads();
  if (tid < 32) {
    const float* kr = KVA + (size_t)t * (kKvLora + kDR) + kKvLora;
    float x1 = kr[tid], x2 = kr[32 + tid];
    KR[(size_t)t * kDR + tid]      = x1 * cs[tid] - x2 * sn[tid];
    KR[(size_t)t * kDR + 32 + tid] = x2 * cs[tid] + x1 * sn[tid];
  }
  for (int it = tid; it < kH * 32; it += 64) {
    int h = it >> 5, i = it & 31;
    float* qr = Q + ((size_t)t * kH + h) * (kDN + kDR) + kDN;
    float x1 = qr[i], x2 = qr[32 + i];
    qr[i]      = x1 * cs[i] - x2 * sn[i];
    qr[32 + i] = x2 * cs[i] + x1 * sn[i];
  }
}

// ---------------- fused indexer scores + exact stable top-k -> 2048-bit mask/row ----------------
__global__ __launch_bounds__(256) void isc_topk_kernel(const float* __restrict__ QI,
                                                       const float* __restrict__ KI,
                                                       const float* __restrict__ WGT,
                                                       unsigned* __restrict__ SEL) {
  int row = blockIdx.x;          // b*S + q
  int q = row & (kS - 1);
  int b = row >> 11;
  int L = q + 1;
  unsigned* selrow = SEL + (size_t)row * (kS / 32);
  int tid = threadIdx.x;
  if (L <= kTopK) {  // all causal keys selected
    if (tid < kS / 32) {
      int base = tid * 32;
      unsigned w;
      if (base + 32 <= L) w = 0xFFFFFFFFu;
      else if (base >= L) w = 0u;
      else w = (1u << (L - base)) - 1u;
      selrow[tid] = w;
    }
    return;
  }
  __shared__ __align__(16) float qrow[kHI * kDI];
  __shared__ float wg[kHI];
  __shared__ unsigned keys[kS];
  __shared__ unsigned hist[256];
  __shared__ unsigned msk[kS / 32];
  __shared__ unsigned pick[2];
  for (int i = tid; i < kHI * kDI; i += 256) qrow[i] = QI[(size_t)row * (kHI * kDI) + i];
  if (tid < kHI) wg[tid] = WGT[(size_t)row * kHI + tid];
  if (tid < kS / 32) msk[tid] = 0u;
  __syncthreads();
  // scores -> sortable keys
  for (int k = tid; k < L; k += 256) {
    const float* kp = KI + (size_t)(b * kS + k) * kDI;
    float d[kHI] = {};
#pragma unroll 4
    for (int i = 0; i < 32; ++i) {
      float4 kv4 = *(const float4*)(kp + i * 4);
#pragma unroll
      for (int h = 0; h < kHI; ++h) {
        float4 q4 = *(const float4*)&qrow[h * kDI + i * 4];
        d[h] += q4.x * kv4.x + q4.y * kv4.y + q4.z * kv4.z + q4.w * kv4.w;
      }
    }
    float sc = 0.0f;
#pragma unroll
    for (int h = 0; h < kHI; ++h) sc += fmaxf(d[h], 0.0f) * wg[h];
    unsigned u = __float_as_uint(sc);
    keys[k] = (u & 0x80000000u) ? ~u : (u | 0x80000000u);  // order-preserving map
  }
  __syncthreads();
  // 4-pass radix select: exact key T of the kTopK-th largest + tie budget
  unsigned prefix = 0u;
  int r = kTopK;
  for (int shift = 24; shift >= 0; shift -= 8) {
    hist[tid] = 0u;
    __syncthreads();
    unsigned hm = (shift == 24) ? 0u : (0xFFFFFFFFu << (shift + 8));
    for (int k = tid; k < L; k += 256) {
      unsigned key = keys[k];
      if ((key & hm) == (prefix & hm)) atomicAdd(&hist[(key >> shift) & 255u], 1u);
    }
    __syncthreads();
    if (tid == 0) {
      int rr = r, bsel = 0;
      for (int bb = 255; bb >= 0; --bb) {
        int c = (int)hist[bb];
        if (rr <= c) { bsel = bb; break; }
        rr -= c;
      }
      pick[0] = (unsigned)bsel;
      pick[1] = (unsigned)rr;
    }
    __syncthreads();
    prefix |= pick[0] << shift;
    r = (int)pick[1];
    __syncthreads();
  }
  unsigned T = prefix;
  int ties_take = r;   // stable: lowest indices first
  int base = tid * 8;
  int cnt = 0;
#pragma unroll
  for (int j = 0; j < 8; ++j) {
    int k = base + j;
    if (k < L && keys[k] == T) ++cnt;
  }
  hist[tid] = (unsigned)cnt;
  __syncthreads();
  if (tid == 0) {
    unsigned run = 0;
    for (int t = 0; t < 256; ++t) { unsigned c = hist[t]; hist[t] = run; run += c; }
  }
  __syncthreads();
  int trank = (int)hist[tid];
  unsigned bits = 0u;
#pragma unroll
  for (int j = 0; j < 8; ++j) {
    int k = base + j;
    if (k < L) {
      unsigned key = keys[k];
      bool s;
      if (key > T) s = true;
      else if (key == T) { s = trank < ties_take; ++trank; }
      else s = false;
      if (s) bits |= (1u << j);
    }
  }
  atomicOr(&msk[tid >> 2], bits << ((tid & 3) * 8));
  __syncthreads();
  if (tid < kS / 32) selrow[tid] = msk[tid];
}

// ---------------- masked attention, one (b,h,q) per block ----------------
__global__ __launch_bounds__(256) void attn_kernel(const float* __restrict__ Q,
                                                   const float* __restrict__ KV,
                                                   const float* __restrict__ KR,
                                                   const unsigned* __restrict__ SEL,
                                                   float* __restrict__ CTX) {
  int q = blockIdx.x, h = blockIdx.y, b = blockIdx.z;
  int row = b * kS + q;
  int L = q + 1;
  int tid = threadIdx.x;
  __shared__ __align__(16) float qs[192];
  __shared__ float pl[kS];
  __shared__ float red[256];
  __shared__ float c2[128];
  const float* qp = Q + ((size_t)row * kH + h) * (kDN + kDR);
  if (tid < 192) qs[tid] = qp[tid];
  __syncthreads();
  const unsigned* selrow = SEL + (size_t)row * (kS / 32);
  const float scale = 0.07216878364870323f;  // 1/sqrt(192)
  float lmax = -3.0e38f;
  for (int k = tid; k < L; k += 256) {
    float lg = kNeg;
    if ((selrow[k >> 5] >> (k & 31)) & 1u) {
      const float* kn = KV + ((size_t)(b * kS + k) * kH + h) * (kDN + kDV);
      const float* kr = KR + (size_t)(b * kS + k) * kDR;
      float dot = 0.0f;
#pragma unroll
      for (int i = 0; i < 32; ++i) {
        float4 k4 = *(const float4*)(kn + i * 4);
        float4 q4 = *(const float4*)(qs + i * 4);
        dot += k4.x * q4.x + k4.y * q4.y + k4.z * q4.z + k4.w * q4.w;
      }
#pragma unroll
      for (int i = 0; i < 16; ++i) {
        float4 k4 = *(const float4*)(kr + i * 4);
        float4 q4 = *(const float4*)(qs + 128 + i * 4);
        dot += k4.x * q4.x + k4.y * q4.y + k4.z * q4.z + k4.w * q4.w;
      }
      lg = dot * scale;
    }
    pl[k] = lg;
    lmax = fmaxf(lmax, lg);
  }
  red[tid] = lmax; __syncthreads();
  for (int s = 128; s >= 1; s >>= 1) {
    if (tid < s) red[tid] = fmaxf(red[tid], red[tid + s]);
    __syncthreads();
  }
  float m = red[0];
  __syncthreads();
  float lsum = 0.0f;
  for (int k = tid; k < L; k += 256) {
    float p = expf(pl[k] - m);
    pl[k] = p;
    lsum += p;
  }
  red[tid] = lsum; __syncthreads();
  for (int s = 128; s >= 1; s >>= 1) {
    if (tid < s) red[tid] += red[tid + s];
    __syncthreads();
  }
  float invs = 1.0f / red[0];
  __syncthreads();
  int d = tid & 127, half = tid >> 7;
  float acc = 0.0f;
  for (int k = half; k < L; k += 2) {
    float p = pl[k];
    if (p != 0.0f)  // wave-uniform (all lanes share k)
      acc += p * KV[((size_t)(b * kS + k) * kH + h) * (kDN + kDV) + kDN + d];
  }
  if (half == 1) c2[d] = acc;
  __syncthreads();
  if (half == 0) CTX[(size_t)row * (kH * kDV) + h * kDV + d] = (acc + c2[d]) * invs;
}

extern "C" void kernel_launch(void* const* d_in, const int* in_sizes, int n_in,
                              void* d_out, int out_size, void* d_ws, size_t ws_size,
                              hipStream_t stream) {
  (void)in_sizes; (void)n_in;

  const float* hidden = (const float*)d_in[0];
  const float* Wqa    = (const float*)d_in[1];
  const float* qnw    = (const float*)d_in[2];
  const float* Wqb    = (const float*)d_in[3];
  const float* Wkva   = (const float*)d_in[4];
  const float* kvnw   = (const float*)d_in[5];
  const float* Wkvb   = (const float*)d_in[6];
  const float* Wiq    = (const float*)d_in[7];
  const float* Wik    = (const float*)d_in[8];
  const float* Wig    = (const float*)d_in[9];
  const float* Wo     = (const float*)d_in[10];
  const int*   pos    = (const int*)d_in[11];
  float* ws  = (float*)d_ws;
  float* out = (float*)d_out;

  if (ws_size < OFF_END * sizeof(float)) {
    // visible failure: absmax will read ~54321 -> workspace too small
    fill_kernel<<<dim3((out_size + 255) / 256), dim3(256), 0, stream>>>(out, out_size, 54321.0f);
    return;
  }

  float* scWqa  = ws + SC_WQA;
  float* scWqb  = ws + SC_WQB;
  float* scWkva = ws + SC_WKVA;
  float* scWkvb = ws + SC_WKVB;
  float* scWo   = ws + SC_WO;
  float* scHid  = ws + SC_HID;
  float* scCtx  = ws + SC_CTX;
  float* qa     = ws + OFF_R1;     // t1-t3
  float* qi     = ws + OFF_R1;     // t8-t9
  float* ctx    = ws + OFF_R1;     // t10-t11 (8.4M)
  float* qbuf   = ws + OFF_QBUF;
  float* kva    = ws + OFF_R2;     // t4-t7
  unsigned* sel = (unsigned*)(ws + OFF_R2);  // t9-t10
  float* ckv    = ws + OFF_R3;     // t5-t6
  float* ki     = ws + OFF_R3;     // t8-t9
  float* wgt    = ws + OFF_R3 + (size_t)kNTok * kDI;
  float* krope  = ws + OFF_KR;
  float* kvbuf  = ws + OFF_KV;

  // weight block scales (128x128)
  weight_scale_kernel<<<dim3(16, 8),  dim3(256), 0, stream>>>(Wqa,  scWqa,  kQLora, kDH);
  weight_scale_kernel<<<dim3(8, 24),  dim3(256), 0, stream>>>(Wqb,  scWqb,  kH * (kDN + kDR), kQLora);
  weight_scale_kernel<<<dim3(16, 5),  dim3(256), 0, stream>>>(Wkva, scWkva, kKvLora + kDR, kDH);
  weight_scale_kernel<<<dim3(4, 32),  dim3(256), 0, stream>>>(Wkvb, scWkvb, kH * (kDN + kDV), kKvLora);
  weight_scale_kernel<<<dim3(16, 16), dim3(256), 0, stream>>>(Wo,   scWo,   kDH, kH * kDV);
  // hidden activation scales
  act_scale_kernel<<<dim3(16384), dim3(256), 0, stream>>>(hidden, scHid, kNTok * (kDH / 128));

  // q_a = qdq(hidden) @ qdq(Wqa)^T ; RMS+qdq in place
  gemm_kernel<true, true><<<dim3(16, 64), dim3(256), 0, stream>>>(hidden, scHid, Wqa, scWqa, qa, kQLora, kDH, 1.0f);
  rms_qdq_kernel<<<dim3(kNTok), dim3(256), 0, stream>>>(qa, qnw, qa, kQLora, kQLora, kQLora);
  // q = qa @ qdq(Wqb)^T
  gemm_kernel<false, true><<<dim3(48, 64), dim3(256), 0, stream>>>(qa, nullptr, Wqb, scWqb, qbuf, kH * (kDN + kDR), kQLora, 1.0f);
  // kv_a = qdq(hidden) @ qdq(Wkva)^T ; c_kv RMS+qdq
  gemm_kernel<true, true><<<dim3(9, 64), dim3(256), 0, stream>>>(hidden, scHid, Wkva, scWkva, kva, kKvLora + kDR, kDH, 1.0f);
  rms_qdq_kernel<<<dim3(kNTok), dim3(256), 0, stream>>>(kva, kvnw, ckv, kKvLora, kKvLora + kDR, kKvLora);
  // kv = ckv @ qdq(Wkvb)^T
  gemm_kernel<false, true><<<dim3(64, 64), dim3(256), 0, stream>>>(ckv, nullptr, Wkvb, scWkvb, kvbuf, kH * (kDN + kDV), kKvLora, 1.0f);
  // RoPE (q in place; k_rope -> krope)  [after qbuf GEMM, before kva region reuse]
  rope_kernel<<<dim3(kNTok), dim3(64), 0, stream>>>(qbuf, kva, krope, pos);

  // indexer projections (raw hidden)
  gemm_kernel<false, false><<<dim3(16, 64), dim3(256), 0, stream>>>(hidden, nullptr, Wiq, nullptr, qi, kHI * kDI, kDH, 1.0f);
  gemm_kernel<false, false><<<dim3(2, 64),  dim3(256), 0, stream>>>(hidden, nullptr, Wik, nullptr, ki, kDI, kDH, 1.0f);
  gemm_kernel<false, false><<<dim3(1, 64),  dim3(256), 0, stream>>>(hidden, nullptr, Wig, nullptr, wgt, kHI, kDH, 0.35355339059327373f);

  // fused indexer scores + exact stable top-k -> selection mask
  isc_topk_kernel<<<dim3(kNTok), dim3(256), 0, stream>>>(qi, ki, wgt, sel);

  // masked attention
  attn_kernel<<<dim3(kS, kH, kB), dim3(256), 0, stream>>>(qbuf, kvbuf, krope, sel, ctx);

  // output projection: qdq(ctx) @ qdq(Wo)^T
  act_scale_kernel<<<dim3(16384), dim3(256), 0, stream>>>(ctx, scCtx, kNTok * ((kH * kDV) / 128));
  gemm_kernel<true, true><<<dim3(32, 64), dim3(256), 0, stream>>>(ctx, scCtx, Wo, scWo, out, kDH, kH * kDV, 1.0f);
}

// Round 3
// 5568.706 us; speedup vs baseline: 4.9833x; 4.9833x over previous
//
#include <hip/hip_runtime.h>
#include <math.h>

namespace {
constexpr int kB = 2, kS = 2048, kDH = 2048, kH = 16, kDN = 128, kDR = 64, kDV = 128;
constexpr int kKvLora = 512, kQLora = 1024, kHI = 8, kDI = 128, kTopK = 1024;
constexpr int kNTok = kB * kS;             // 4096
constexpr float kNeg = -1e30f;

// ---- workspace layout (float elements), ~170.4 MB total ----
constexpr size_t SC_WQA  = 0;        // 8*16   = 128
constexpr size_t SC_WQB  = 128;      // 24*8   = 192
constexpr size_t SC_WKVA = 320;      // 5*16   = 80
constexpr size_t SC_WKVB = 400;      // 32*4   = 128
constexpr size_t SC_WO   = 528;      // 16*16  = 256
constexpr size_t SC_HID  = 784;      // 4096*16 = 65536
constexpr size_t SC_CTX  = 66320;    // 4096*16 = 65536
constexpr size_t OFF_R1  = 132096;                     // qa(4.2M)/qi(4.2M)/ctx(8.4M)
constexpr size_t OFF_QBUF = OFF_R1 + 8388608;          // 12582912
constexpr size_t OFF_R2  = OFF_QBUF + 12582912;        // kva(2359296) then sel(131072 u32)
constexpr size_t OFF_R3  = OFF_R2 + 2359296;           // ckv(2097152) then ki(524288)+wgt(32768)
constexpr size_t OFF_KR  = OFF_R3 + 2097152;           // 262144
constexpr size_t OFF_KV  = OFF_KR + 262144;            // 16777216
constexpr size_t OFF_END = OFF_KV + 16777216;          // 42599424 floats
} // namespace

// Exact e4m3fn round-to-nearest-even quant-dequant for |x| <= 448 (incl. subnormals).
__device__ __forceinline__ float fp8_e4m3_qdq(float x) {
  float ax = fabsf(x);
  int e;
  (void)frexpf(ax, &e);          // ax = m * 2^e, m in [0.5,1)
  int ee = e - 1;                // floor(log2 ax)
  if (ee < -6) ee = -6;          // subnormal regime
  float q = ldexpf(1.0f, ee - 3);// quantization step (3 mantissa bits)
  float y = rintf(ax / q) * q;   // exact: q is a power of 2
  return (x < 0.0f) ? -y : y;
}

// scale = exp2(ceil(log2(amax/448))) computed exactly at the bit level
__device__ __forceinline__ float act_scale_from_amax(float amax) {
  float t = amax / 448.0f;
  unsigned u = __float_as_uint(t);
  int e = (int)((u >> 23) & 255u) - 127;
  if (u & 0x7fffffu) e += 1;
  return __uint_as_float((unsigned)(e + 127) << 23);
}

__device__ __forceinline__ float clamp448(float v) {
  return fminf(fmaxf(v, -448.0f), 448.0f);
}

__global__ __launch_bounds__(256) void fill_kernel(float* p, int n, float v) {
  int i = blockIdx.x * 256 + threadIdx.x;
  if (i < n) p[i] = v;
}

// ---------------- weight 128x128-block scale: Bsc[ob*KB+kb] = max(amax,1e-4)/448 ----------------
__global__ __launch_bounds__(256) void weight_scale_kernel(const float* __restrict__ W,
                                                           float* __restrict__ SC, int O, int I) {
  int kb = blockIdx.x, ob = blockIdx.y;
  int bo = ob * 128, bi = kb * 128;
  int tid = threadIdx.x;
  __shared__ float red[256];
  float am = 0.0f;
  for (int idx = tid; idx < 128 * 128; idx += 256) {
    int r = bo + (idx >> 7), c = bi + (idx & 127);
    if (r < O) am = fmaxf(am, fabsf(W[(size_t)r * I + c]));
  }
  red[tid] = am; __syncthreads();
  for (int s = 128; s >= 1; s >>= 1) {
    if (tid < s) red[tid] = fmaxf(red[tid], red[tid + s]);
    __syncthreads();
  }
  if (tid == 0) SC[(size_t)ob * gridDim.x + kb] = fmaxf(red[0], 1e-4f) / 448.0f;
}

// ---------------- activation per-(row,128-block) power-of-2 scale ----------------
__global__ __launch_bounds__(256) void act_scale_kernel(const float* __restrict__ X,
                                                        float* __restrict__ SC, int nblk) {
  int wid = blockIdx.x * 4 + (threadIdx.x >> 6);
  int lane = threadIdx.x & 63;
  if (wid >= nblk) return;
  const float* x = X + (size_t)wid * 128;
  float am = fmaxf(fabsf(x[lane]), fabsf(x[lane + 64]));
#pragma unroll
  for (int m = 32; m >= 1; m >>= 1) am = fmaxf(am, __shfl_xor(am, m, 64));
  if (lane == 0) SC[wid] = act_scale_from_amax(fmaxf(am, 1e-4f));
}

// ---------------- fused RMSNorm + activation qdq (per row) ----------------
__global__ __launch_bounds__(256) void rms_qdq_kernel(const float* __restrict__ X,
                                                      const float* __restrict__ G,
                                                      float* __restrict__ Y,
                                                      int C, int xs, int ys) {
  int row = blockIdx.x, tid = threadIdx.x;
  __shared__ float xr[1024];
  __shared__ float red[256];
  const float* x = X + (size_t)row * xs;
  float ssq = 0.0f;
  for (int i = tid; i < C; i += 256) { float v = x[i]; xr[i] = v; ssq += v * v; }
  red[tid] = ssq; __syncthreads();
  for (int s = 128; s >= 1; s >>= 1) { if (tid < s) red[tid] += red[tid + s]; __syncthreads(); }
  float inv = 1.0f / sqrtf(red[0] / (float)C + 1e-6f);
  __syncthreads();
  int wv = tid >> 6, lane = tid & 63;
  for (int blk = wv; blk < C / 128; blk += 4) {
    int i0 = blk * 128 + lane, i1 = i0 + 64;
    float y0 = xr[i0] * inv * G[i0];
    float y1 = xr[i1] * inv * G[i1];
    float am = fmaxf(fabsf(y0), fabsf(y1));
#pragma unroll
    for (int m = 32; m >= 1; m >>= 1) am = fmaxf(am, __shfl_xor(am, m, 64));
    am = fmaxf(am, 1e-4f);
    float scale = act_scale_from_amax(am);
    Y[(size_t)row * ys + i0] = fp8_e4m3_qdq(clamp448(y0 / scale)) * scale;
    Y[(size_t)row * ys + i1] = fp8_e4m3_qdq(clamp448(y1 / scale)) * scale;
  }
}

// ---------------- f32 GEMM with optional fused fp8 qdq on A and/or B ----------------
// C[m,n] = alpha * sum_k qdqA(A[m,k]) * qdqB(B[n,k]);  M fixed = kNTok
template <bool AQ, bool BQ>
__global__ __launch_bounds__(256) void gemm_kernel(const float* __restrict__ A,
                                                   const float* __restrict__ Asc,
                                                   const float* __restrict__ Bw,
                                                   const float* __restrict__ Bsc,
                                                   float* __restrict__ C,
                                                   int N, int K, float alpha) {
  __shared__ __align__(16) float As[16][68];
  __shared__ __align__(16) float Bs[16][68];
  int n0 = blockIdx.x * 64;
  int m0 = blockIdx.y * 64;
  int tid = threadIdx.x;
  int tx = tid & 15, ty = tid >> 4;
  int KB = K >> 7;
  float acc[4][4] = {};
  for (int k0 = 0; k0 < K; k0 += 16) {
    int kb = k0 >> 7;
#pragma unroll
    for (int t = 0; t < 4; ++t) {
      int idx = tid + t * 256;
      int rr = idx >> 4;   // 0..63
      int kk = idx & 15;
      float a = A[(size_t)(m0 + rr) * K + (k0 + kk)];
      if (AQ) {
        float s = Asc[(size_t)(m0 + rr) * KB + kb];
        a = fp8_e4m3_qdq(clamp448(a / s)) * s;
      }
      As[kk][rr] = a;
      float b = 0.0f;
      if (n0 + rr < N) {
        b = Bw[(size_t)(n0 + rr) * K + (k0 + kk)];
        if (BQ) {
          float s = Bsc[(size_t)((n0 + rr) >> 7) * KB + kb];
          b = fp8_e4m3_qdq(clamp448(b / s)) * s;
        }
      }
      Bs[kk][rr] = b;
    }
    __syncthreads();
#pragma unroll
    for (int kk = 0; kk < 16; ++kk) {
      float4 a = *(const float4*)&As[kk][ty * 4];
      float4 b = *(const float4*)&Bs[kk][tx * 4];
      float av[4] = {a.x, a.y, a.z, a.w};
      float bv[4] = {b.x, b.y, b.z, b.w};
#pragma unroll
      for (int i = 0; i < 4; ++i)
#pragma unroll
        for (int j = 0; j < 4; ++j) acc[i][j] += av[i] * bv[j];
    }
    __syncthreads();
  }
#pragma unroll
  for (int i = 0; i < 4; ++i) {
    int m = m0 + ty * 4 + i;
#pragma unroll
    for (int j = 0; j < 4; ++j) {
      int n = n0 + tx * 4 + j;
      if (n < N) C[(size_t)m * N + n] = alpha * acc[i][j];
    }
  }
}

// ---------------- RoPE: q (in place, per head) and k_rope -> KR ----------------
__global__ __launch_bounds__(64) void rope_kernel(float* __restrict__ Q,
                                                  const float* __restrict__ KVA,
                                                  float* __restrict__ KR,
                                                  const int* __restrict__ POS) {
  int t = blockIdx.x;  // b*S + s
  int tid = threadIdx.x;
  __shared__ float cs[32], sn[32];
  if (tid < 32) {
    int pos = POS[t];
    double inv = pow(10000.0, -((double)(2 * tid) / 64.0));
    float ang = (float)pos * (float)inv;
    cs[tid] = cosf(ang);
    sn[tid] = sinf(ang);
  }
  __syncthreads();
  if (tid < 32) {
    const float* kr = KVA + (size_t)t * (kKvLora + kDR) + kKvLora;
    float x1 = kr[tid], x2 = kr[32 + tid];
    KR[(size_t)t * kDR + tid]      = x1 * cs[tid] - x2 * sn[tid];
    KR[(size_t)t * kDR + 32 + tid] = x2 * cs[tid] + x1 * sn[tid];
  }
  for (int it = tid; it < kH * 32; it += 64) {
    int h = it >> 5, i = it & 31;
    float* qr = Q + ((size_t)t * kH + h) * (kDN + kDR) + kDN;
    float x1 = qr[i], x2 = qr[32 + i];
    qr[i]      = x1 * cs[i] - x2 * sn[i];
    qr[32 + i] = x2 * cs[i] + x1 * sn[i];
  }
}

// ---------------- fused indexer scores + exact stable top-k -> 2048-bit mask/row ----------------
__global__ __launch_bounds__(256) void isc_topk_kernel(const float* __restrict__ QI,
                                                       const float* __restrict__ KI,
                                                       const float* __restrict__ WGT,
                                                       unsigned* __restrict__ SEL) {
  int row = blockIdx.x;          // b*S + q
  int q = row & (kS - 1);
  int b = row >> 11;
  int L = q + 1;
  unsigned* selrow = SEL + (size_t)row * (kS / 32);
  int tid = threadIdx.x;
  if (L <= kTopK) {  // all causal keys selected
    if (tid < kS / 32) {
      int base = tid * 32;
      unsigned w;
      if (base + 32 <= L) w = 0xFFFFFFFFu;
      else if (base >= L) w = 0u;
      else w = (1u << (L - base)) - 1u;
      selrow[tid] = w;
    }
    return;
  }
  __shared__ __align__(16) float qrow[kHI * kDI];
  __shared__ float wg[kHI];
  __shared__ unsigned keys[kS];
  __shared__ unsigned hist[256];
  __shared__ unsigned msk[kS / 32];
  __shared__ unsigned pick[2];
  for (int i = tid; i < kHI * kDI; i += 256) qrow[i] = QI[(size_t)row * (kHI * kDI) + i];
  if (tid < kHI) wg[tid] = WGT[(size_t)row * kHI + tid];
  if (tid < kS / 32) msk[tid] = 0u;
  __syncthreads();
  // scores -> sortable keys
  for (int k = tid; k < L; k += 256) {
    const float* kp = KI + (size_t)(b * kS + k) * kDI;
    float d[kHI] = {};
#pragma unroll 4
    for (int i = 0; i < 32; ++i) {
      float4 kv4 = *(const float4*)(kp + i * 4);
#pragma unroll
      for (int h = 0; h < kHI; ++h) {
        float4 q4 = *(const float4*)&qrow[h * kDI + i * 4];
        d[h] += q4.x * kv4.x + q4.y * kv4.y + q4.z * kv4.z + q4.w * kv4.w;
      }
    }
    float sc = 0.0f;
#pragma unroll
    for (int h = 0; h < kHI; ++h) sc += fmaxf(d[h], 0.0f) * wg[h];
    unsigned u = __float_as_uint(sc);
    keys[k] = (u & 0x80000000u) ? ~u : (u | 0x80000000u);  // order-preserving map
  }
  __syncthreads();
  // 4-pass radix select: exact key T of the kTopK-th largest + tie budget
  unsigned prefix = 0u;
  int r = kTopK;
  for (int shift = 24; shift >= 0; shift -= 8) {
    hist[tid] = 0u;
    __syncthreads();
    unsigned hm = (shift == 24) ? 0u : (0xFFFFFFFFu << (shift + 8));
    for (int k = tid; k < L; k += 256) {
      unsigned key = keys[k];
      if ((key & hm) == (prefix & hm)) atomicAdd(&hist[(key >> shift) & 255u], 1u);
    }
    __syncthreads();
    if (tid == 0) {
      int rr = r, bsel = 0;
      for (int bb = 255; bb >= 0; --bb) {
        int c = (int)hist[bb];
        if (rr <= c) { bsel = bb; break; }
        rr -= c;
      }
      pick[0] = (unsigned)bsel;
      pick[1] = (unsigned)rr;
    }
    __syncthreads();
    prefix |= pick[0] << shift;
    r = (int)pick[1];
    __syncthreads();
  }
  unsigned T = prefix;
  int ties_take = r;   // stable: lowest indices first
  int base = tid * 8;
  int cnt = 0;
#pragma unroll
  for (int j = 0; j < 8; ++j) {
    int k = base + j;
    if (k < L && keys[k] == T) ++cnt;
  }
  hist[tid] = (unsigned)cnt;
  __syncthreads();
  if (tid == 0) {
    unsigned run = 0;
    for (int t = 0; t < 256; ++t) { unsigned c = hist[t]; hist[t] = run; run += c; }
  }
  __syncthreads();
  int trank = (int)hist[tid];
  unsigned bits = 0u;
#pragma unroll
  for (int j = 0; j < 8; ++j) {
    int k = base + j;
    if (k < L) {
      unsigned key = keys[k];
      bool s;
      if (key > T) s = true;
      else if (key == T) { s = trank < ties_take; ++trank; }
      else s = false;
      if (s) bits |= (1u << j);
    }
  }
  atomicOr(&msk[tid >> 2], bits << ((tid & 3) * 8));
  __syncthreads();
  if (tid < kS / 32) selrow[tid] = msk[tid];
}

// ---------------- tiled flash attention: block = (b, h, 64-query tile) ----------------
// Q rows 192 (nope|rope), K = kv nope 128 + krope 64, V = kv[128..255].
// Online softmax over 64-key tiles; selection mask comes from SEL (sel implies causal).
__global__ __launch_bounds__(256) void attn_kernel(const float* __restrict__ Q,
                                                   const float* __restrict__ KV,
                                                   const float* __restrict__ KR,
                                                   const unsigned* __restrict__ SEL,
                                                   float* __restrict__ CTX) {
  const int q0 = blockIdx.x * 64;
  const int h  = blockIdx.y;
  const int b  = blockIdx.z;
  const int tid = threadIdx.x;
  const int tq = tid >> 4, tk = tid & 15;          // 16x16 thread grid
  const float scale = 0.07216878364870323f;        // 1/sqrt(192)

  // LDS: bufA holds Qt+Kt (S phase) aliased with Vs (PV phase)
  __shared__ __align__(16) float bufA[2 * 64 * 68];      // 34816 B
  __shared__ __align__(16) float Pt[64][68];             // 17408 B (P transposed [k][q])
  __shared__ unsigned selw[64][2];
  __shared__ float mrow[64], lrow[64], frow[64];
  float (*Qt)[68] = (float(*)[68])bufA;                  // [d][q]
  float (*Kt)[68] = (float(*)[68])(bufA + 64 * 68);      // [d][k]
  float (*Vs)[128] = (float(*)[128])bufA;                // [k][d] (aliased)

  float O[4][8] = {};
  float acc[4][4] = {};
  if (tid < 64) { mrow[tid] = kNeg; lrow[tid] = 0.0f; }

  const int nkt = (q0 >> 6) + 1;
  for (int kt = 0; kt < nkt; ++kt) {
    const int k0 = kt * 64;
    // ---- stage selection-mask words for this tile ----
    __syncthreads();
    if (tid < 128) {
      int r = tid >> 1, w = tid & 1;
      selw[r][w] = SEL[(size_t)(b * kS + q0 + r) * (kS / 32) + (k0 >> 5) + w];
    }
    // ---- S = Q K^T over 3 d-chunks of 64 ----
#pragma unroll
    for (int dc = 0; dc < 3; ++dc) {
      __syncthreads();
      // stage Qt[dl][r], Kt[dl][r] transposed; 1024 float4 tasks each
#pragma unroll
      for (int t = 0; t < 4; ++t) {
        int task = t * 256 + tid;
        int r = task >> 4, d4 = task & 15;
        int d = dc * 64 + d4 * 4;
        float4 qv = *(const float4*)&Q[(((size_t)(b * kS + q0 + r) * kH) + h) * (kDN + kDR) + d];
        Qt[d4 * 4 + 0][r] = qv.x; Qt[d4 * 4 + 1][r] = qv.y;
        Qt[d4 * 4 + 2][r] = qv.z; Qt[d4 * 4 + 3][r] = qv.w;
        float4 kv4;
        if (dc < 2) {
          kv4 = *(const float4*)&KV[(((size_t)(b * kS + k0 + r) * kH) + h) * (kDN + kDV) + d];
        } else {
          kv4 = *(const float4*)&KR[(size_t)(b * kS + k0 + r) * kDR + d4 * 4];
        }
        Kt[d4 * 4 + 0][r] = kv4.x; Kt[d4 * 4 + 1][r] = kv4.y;
        Kt[d4 * 4 + 2][r] = kv4.z; Kt[d4 * 4 + 3][r] = kv4.w;
      }
      __syncthreads();
#pragma unroll 8
      for (int dl = 0; dl < 64; ++dl) {
        float4 qa = *(const float4*)&Qt[dl][tq * 4];
        float4 kb = *(const float4*)&Kt[dl][tk * 4];
        float av[4] = {qa.x, qa.y, qa.z, qa.w};
        float bv[4] = {kb.x, kb.y, kb.z, kb.w};
#pragma unroll
        for (int i = 0; i < 4; ++i)
#pragma unroll
          for (int j = 0; j < 4; ++j) acc[i][j] += av[i] * bv[j];
      }
    }
    // ---- mask + write P^T ----
#pragma unroll
    for (int i = 0; i < 4; ++i) {
      int r = tq * 4 + i;
#pragma unroll
      for (int j = 0; j < 4; ++j) {
        int c = tk * 4 + j;
        bool bit = (selw[r][c >> 5] >> (c & 31)) & 1u;
        Pt[c][r] = bit ? acc[i][j] * scale : kNeg;
        acc[i][j] = 0.0f;
      }
    }
    __syncthreads();
    // ---- online softmax: 4 threads per row ----
    {
      int r = tid >> 2, p = tid & 3;
      float mo = mrow[r];
      float tmax = kNeg;
#pragma unroll
      for (int c = p * 16; c < p * 16 + 16; ++c) tmax = fmaxf(tmax, Pt[c][r]);
      tmax = fmaxf(tmax, __shfl_xor(tmax, 1, 64));
      tmax = fmaxf(tmax, __shfl_xor(tmax, 2, 64));
      float mn = fmaxf(mo, tmax);
      float sum = 0.0f;
#pragma unroll
      for (int c = p * 16; c < p * 16 + 16; ++c) {
        float lx = Pt[c][r];
        float pp = (lx < -1e29f) ? 0.0f : expf(lx - mn);
        Pt[c][r] = pp;
        sum += pp;
      }
      sum += __shfl_xor(sum, 1, 64);
      sum += __shfl_xor(sum, 2, 64);
      if (p == 0) {
        float f = expf(mo - mn);   // mo=mn=kNeg -> 1; mo=kNeg,mn real -> 0
        frow[r] = f;
        lrow[r] = lrow[r] * f + sum;
        mrow[r] = mn;
      }
    }
    __syncthreads();
    // ---- rescale O, stage V (aliases Qt/Kt) ----
#pragma unroll
    for (int i = 0; i < 4; ++i) {
      float f = frow[tq * 4 + i];
#pragma unroll
      for (int j = 0; j < 8; ++j) O[i][j] *= f;
    }
#pragma unroll
    for (int t = 0; t < 8; ++t) {
      int task = t * 256 + tid;
      int kr = task >> 5, d4 = task & 31;
      float4 vv = *(const float4*)&KV[(((size_t)(b * kS + k0 + kr) * kH) + h) * (kDN + kDV) + kDN + d4 * 4];
      *(float4*)&Vs[kr][d4 * 4] = vv;
    }
    __syncthreads();
    // ---- PV accumulate ----
#pragma unroll 4
    for (int c = 0; c < 64; ++c) {
      float4 pa = *(const float4*)&Pt[c][tq * 4];
      float pv[4] = {pa.x, pa.y, pa.z, pa.w};
#pragma unroll
      for (int j = 0; j < 8; ++j) {
        float v = Vs[c][tk + 16 * j];
#pragma unroll
        for (int i = 0; i < 4; ++i) O[i][j] += pv[i] * v;
      }
    }
  }
  // ---- normalize + write ctx ----
  __syncthreads();
#pragma unroll
  for (int i = 0; i < 4; ++i) {
    int r = tq * 4 + i;
    float inv = 1.0f / lrow[r];
    size_t base = (size_t)(b * kS + q0 + r) * (kH * kDV) + (size_t)h * kDV;
#pragma unroll
    for (int j = 0; j < 8; ++j) CTX[base + tk + 16 * j] = O[i][j] * inv;
  }
}

extern "C" void kernel_launch(void* const* d_in, const int* in_sizes, int n_in,
                              void* d_out, int out_size, void* d_ws, size_t ws_size,
                              hipStream_t stream) {
  (void)in_sizes; (void)n_in;

  const float* hidden = (const float*)d_in[0];
  const float* Wqa    = (const float*)d_in[1];
  const float* qnw    = (const float*)d_in[2];
  const float* Wqb    = (const float*)d_in[3];
  const float* Wkva   = (const float*)d_in[4];
  const float* kvnw   = (const float*)d_in[5];
  const float* Wkvb   = (const float*)d_in[6];
  const float* Wiq    = (const float*)d_in[7];
  const float* Wik    = (const float*)d_in[8];
  const float* Wig    = (const float*)d_in[9];
  const float* Wo     = (const float*)d_in[10];
  const int*   pos    = (const int*)d_in[11];
  float* ws  = (float*)d_ws;
  float* out = (float*)d_out;

  if (ws_size < OFF_END * sizeof(float)) {
    // visible failure: absmax will read ~54321 -> workspace too small
    fill_kernel<<<dim3((out_size + 255) / 256), dim3(256), 0, stream>>>(out, out_size, 54321.0f);
    return;
  }

  float* scWqa  = ws + SC_WQA;
  float* scWqb  = ws + SC_WQB;
  float* scWkva = ws + SC_WKVA;
  float* scWkvb = ws + SC_WKVB;
  float* scWo   = ws + SC_WO;
  float* scHid  = ws + SC_HID;
  float* scCtx  = ws + SC_CTX;
  float* qa     = ws + OFF_R1;     // t1-t3
  float* qi     = ws + OFF_R1;     // t8-t9
  float* ctx    = ws + OFF_R1;     // t10-t11 (8.4M)
  float* qbuf   = ws + OFF_QBUF;
  float* kva    = ws + OFF_R2;     // t4-t7
  unsigned* sel = (unsigned*)(ws + OFF_R2);  // t9-t10
  float* ckv    = ws + OFF_R3;     // t5-t6
  float* ki     = ws + OFF_R3;     // t8-t9
  float* wgt    = ws + OFF_R3 + (size_t)kNTok * kDI;
  float* krope  = ws + OFF_KR;
  float* kvbuf  = ws + OFF_KV;

  // weight block scales (128x128)
  weight_scale_kernel<<<dim3(16, 8),  dim3(256), 0, stream>>>(Wqa,  scWqa,  kQLora, kDH);
  weight_scale_kernel<<<dim3(8, 24),  dim3(256), 0, stream>>>(Wqb,  scWqb,  kH * (kDN + kDR), kQLora);
  weight_scale_kernel<<<dim3(16, 5),  dim3(256), 0, stream>>>(Wkva, scWkva, kKvLora + kDR, kDH);
  weight_scale_kernel<<<dim3(4, 32),  dim3(256), 0, stream>>>(Wkvb, scWkvb, kH * (kDN + kDV), kKvLora);
  weight_scale_kernel<<<dim3(16, 16), dim3(256), 0, stream>>>(Wo,   scWo,   kDH, kH * kDV);
  // hidden activation scales
  act_scale_kernel<<<dim3(16384), dim3(256), 0, stream>>>(hidden, scHid, kNTok * (kDH / 128));

  // q_a = qdq(hidden) @ qdq(Wqa)^T ; RMS+qdq in place
  gemm_kernel<true, true><<<dim3(16, 64), dim3(256), 0, stream>>>(hidden, scHid, Wqa, scWqa, qa, kQLora, kDH, 1.0f);
  rms_qdq_kernel<<<dim3(kNTok), dim3(256), 0, stream>>>(qa, qnw, qa, kQLora, kQLora, kQLora);
  // q = qa @ qdq(Wqb)^T
  gemm_kernel<false, true><<<dim3(48, 64), dim3(256), 0, stream>>>(qa, nullptr, Wqb, scWqb, qbuf, kH * (kDN + kDR), kQLora, 1.0f);
  // kv_a = qdq(hidden) @ qdq(Wkva)^T ; c_kv RMS+qdq
  gemm_kernel<true, true><<<dim3(9, 64), dim3(256), 0, stream>>>(hidden, scHid, Wkva, scWkva, kva, kKvLora + kDR, kDH, 1.0f);
  rms_qdq_kernel<<<dim3(kNTok), dim3(256), 0, stream>>>(kva, kvnw, ckv, kKvLora, kKvLora + kDR, kKvLora);
  // kv = ckv @ qdq(Wkvb)^T
  gemm_kernel<false, true><<<dim3(64, 64), dim3(256), 0, stream>>>(ckv, nullptr, Wkvb, scWkvb, kvbuf, kH * (kDN + kDV), kKvLora, 1.0f);
  // RoPE (q in place; k_rope -> krope)  [after qbuf GEMM, before kva region reuse]
  rope_kernel<<<dim3(kNTok), dim3(64), 0, stream>>>(qbuf, kva, krope, pos);

  // indexer projections (raw hidden)
  gemm_kernel<false, false><<<dim3(16, 64), dim3(256), 0, stream>>>(hidden, nullptr, Wiq, nullptr, qi, kHI * kDI, kDH, 1.0f);
  gemm_kernel<false, false><<<dim3(2, 64),  dim3(256), 0, stream>>>(hidden, nullptr, Wik, nullptr, ki, kDI, kDH, 1.0f);
  gemm_kernel<false, false><<<dim3(1, 64),  dim3(256), 0, stream>>>(hidden, nullptr, Wig, nullptr, wgt, kHI, kDH, 0.35355339059327373f);

  // fused indexer scores + exact stable top-k -> selection mask
  isc_topk_kernel<<<dim3(kNTok), dim3(256), 0, stream>>>(qi, ki, wgt, sel);

  // tiled flash attention
  attn_kernel<<<dim3(kS / 64, kH, kB), dim3(256), 0, stream>>>(qbuf, kvbuf, krope, sel, ctx);

  // output projection: qdq(ctx) @ qdq(Wo)^T
  act_scale_kernel<<<dim3(16384), dim3(256), 0, stream>>>(ctx, scCtx, kNTok * ((kH * kDV) / 128));
  gemm_kernel<true, true><<<dim3(32, 64), dim3(256), 0, stream>>>(ctx, scCtx, Wo, scWo, out, kDH, kH * kDV, 1.0f);
}

// Round 4
// 2673.277 us; speedup vs baseline: 10.3807x; 2.0831x over previous
//
#include <hip/hip_runtime.h>
#include <math.h>

namespace {
constexpr int kB = 2, kS = 2048, kDH = 2048, kH = 16, kDN = 128, kDR = 64, kDV = 128;
constexpr int kKvLora = 512, kQLora = 1024, kHI = 8, kDI = 128, kTopK = 1024;
constexpr int kNTok = kB * kS;             // 4096
constexpr float kNeg = -1e30f;

constexpr size_t MB = 1ull << 20;
// ---- workspace layout (BYTES) ----
constexpr size_t OFF_SC    = 0;                         // 784 f32 scale tables
constexpr size_t OFF_SEL_B = 4096;                      // 1 MB (4096 rows x 64 u32)
constexpr size_t OFF_WGT_B = OFF_SEL_B + 1048576;       // 128 KB
constexpr size_t OFF_KR_B  = OFF_WGT_B + 131072;        // 1 MB
constexpr size_t OFF_WOB_B = OFF_KR_B + 1048576;        // 8 MB  Wo bf16 (persistent)
constexpr size_t POOL      = OFF_WOB_B + 8388608;       // 10,620,928
// phase A (indexer):
constexpr size_t P_QI    = POOL;                        // 16 MB f32
constexpr size_t P_KI    = POOL + 16 * MB;              // 2 MB f32
constexpr size_t P_HHI   = POOL + 20 * MB;              // 16 MB bf16
constexpr size_t P_HLO   = POOL + 36 * MB;              // 16 MB bf16
constexpr size_t P_WIQH  = POOL + 52 * MB;              // 4 MB
constexpr size_t P_WIQL  = POOL + 56 * MB;              // 4 MB
constexpr size_t P_WIKH  = POOL + 60 * MB;              // 512 KB
constexpr size_t P_WIKL  = POOL + 60 * MB + 524288;     // 512 KB
// phase B:
constexpr size_t P_KVBUF = POOL;                        // 64 MB f32 (written late)
constexpr size_t P_QAB   = POOL;                        // 8 MB bf16 (dead before kvbuf)
constexpr size_t P_QAF   = POOL + 8 * MB;               // 16 MB f32 (dead before kvbuf)
constexpr size_t P_KVA   = POOL + 24 * MB;              // 9.4 MB f32 (dead before kvbuf)
constexpr size_t P_HIDQ  = POOL + 64 * MB;              // 16 MB bf16
constexpr size_t P_WQAB  = POOL + 80 * MB;              // 4 MB
constexpr size_t P_WQBB  = POOL + 84 * MB;              // 6 MB
constexpr size_t P_WKVAB = POOL + 90 * MB;              // 2.5 MB (640 rows pad)
constexpr size_t P_WKVBB = POOL + 92 * MB + 524288;     // 4 MB
constexpr size_t P_CKVB  = POOL + 96 * MB + 524288;     // 4 MB
constexpr size_t P_CTX   = POOL + 64 * MB;              // 32 MB f32 (after hidq/W dead)
constexpr size_t P_CTXB  = POOL + 96 * MB + 524288;     // 16 MB bf16 (after ckv_b dead)
constexpr size_t P_QBUF  = POOL + 100 * MB + 524288;    // 50.3 MB f32
constexpr size_t WS_NEED = P_QBUF + (size_t)kNTok * kH * (kDN + kDR) * 4;  // ~159 MB
} // namespace

typedef __attribute__((ext_vector_type(4))) float f32x4;
typedef __attribute__((ext_vector_type(8))) short bf16x8;
typedef __attribute__((address_space(1))) const void gvoid;
typedef __attribute__((address_space(3))) void lvoid;

// Exact e4m3fn round-to-nearest-even quant-dequant for |x| <= 448 (incl. subnormals).
__device__ __forceinline__ float fp8_e4m3_qdq(float x) {
  float ax = fabsf(x);
  int e;
  (void)frexpf(ax, &e);
  int ee = e - 1;
  if (ee < -6) ee = -6;
  float q = ldexpf(1.0f, ee - 3);
  float y = rintf(ax / q) * q;
  return (x < 0.0f) ? -y : y;
}

__device__ __forceinline__ float act_scale_from_amax(float amax) {
  float t = amax / 448.0f;
  unsigned u = __float_as_uint(t);
  int e = (int)((u >> 23) & 255u) - 127;
  if (u & 0x7fffffu) e += 1;
  return __uint_as_float((unsigned)(e + 127) << 23);
}

__device__ __forceinline__ float clamp448(float v) {
  return fminf(fmaxf(v, -448.0f), 448.0f);
}

__device__ __forceinline__ unsigned short f32_to_bf16(float f) {
  unsigned u = __float_as_uint(f);
  unsigned r = (u + 0x7FFFu + ((u >> 16) & 1u)) >> 16;
  return (unsigned short)r;
}
__device__ __forceinline__ float bf16_to_f32(unsigned short h) {
  return __uint_as_float((unsigned)h << 16);
}

__global__ __launch_bounds__(256) void fill_kernel(float* p, int n, float v) {
  int i = blockIdx.x * 256 + threadIdx.x;
  if (i < n) p[i] = v;
}

// ---------------- weight 128x128-block scale ----------------
__global__ __launch_bounds__(256) void weight_scale_kernel(const float* __restrict__ W,
                                                           float* __restrict__ SC, int O, int I) {
  int kb = blockIdx.x, ob = blockIdx.y;
  int bo = ob * 128, bi = kb * 128;
  int tid = threadIdx.x;
  __shared__ float red[256];
  float am = 0.0f;
  for (int idx = tid; idx < 128 * 128; idx += 256) {
    int r = bo + (idx >> 7), c = bi + (idx & 127);
    if (r < O) am = fmaxf(am, fabsf(W[(size_t)r * I + c]));
  }
  red[tid] = am; __syncthreads();
  for (int s = 128; s >= 1; s >>= 1) {
    if (tid < s) red[tid] = fmaxf(red[tid], red[tid + s]);
    __syncthreads();
  }
  if (tid == 0) SC[(size_t)ob * gridDim.x + kb] = fmaxf(red[0], 1e-4f) / 448.0f;
}

// ---------------- weight -> bf16 quantized values (no scale applied) ----------------
__global__ __launch_bounds__(256) void weight_to_bf16_kernel(const float* __restrict__ W,
                                                             const float* __restrict__ SC,
                                                             unsigned short* __restrict__ WB,
                                                             int O, int I, int Opad) {
  size_t idx = (size_t)blockIdx.x * 256 + threadIdx.x;
  if (idx >= (size_t)Opad * I) return;
  int r = (int)(idx / I), c = (int)(idx % I);
  unsigned short v = 0;
  if (r < O) {
    float s = SC[(size_t)(r >> 7) * (I >> 7) + (c >> 7)];
    float q = fp8_e4m3_qdq(clamp448(W[(size_t)r * I + c] / s));
    v = f32_to_bf16(q);  // exact: e4m3 values fit bf16
  }
  WB[idx] = v;
}

// ---------------- activation qdq -> bf16 (per 128-block pow2 scale; exact) ----------------
__global__ __launch_bounds__(256) void act_to_bf16_kernel(const float* __restrict__ X,
                                                          unsigned short* __restrict__ Y, int nblk) {
  int wid = blockIdx.x * 4 + (threadIdx.x >> 6);
  int lane = threadIdx.x & 63;
  if (wid >= nblk) return;
  const float* x = X + (size_t)wid * 128;
  float v0 = x[lane], v1 = x[lane + 64];
  float am = fmaxf(fabsf(v0), fabsf(v1));
#pragma unroll
  for (int m = 32; m >= 1; m >>= 1) am = fmaxf(am, __shfl_xor(am, m, 64));
  am = fmaxf(am, 1e-4f);
  float s = act_scale_from_amax(am);
  Y[(size_t)wid * 128 + lane]      = f32_to_bf16(fp8_e4m3_qdq(clamp448(v0 / s)) * s);
  Y[(size_t)wid * 128 + 64 + lane] = f32_to_bf16(fp8_e4m3_qdq(clamp448(v1 / s)) * s);
}

// ---------------- f32 -> bf16 hi/lo split ----------------
__global__ __launch_bounds__(256) void split_bf16x2_kernel(const float* __restrict__ X,
                                                           unsigned short* __restrict__ HI,
                                                           unsigned short* __restrict__ LO,
                                                           size_t n) {
  size_t i = (size_t)blockIdx.x * 256 + threadIdx.x;
  if (i >= n) return;
  float x = X[i];
  unsigned short h = f32_to_bf16(x);
  float hf = bf16_to_f32(h);
  HI[i] = h;
  LO[i] = f32_to_bf16(x - hf);
}

// ---------------- fused RMSNorm + activation qdq -> bf16 (per row) ----------------
__global__ __launch_bounds__(256) void rms_qdq_kernel(const float* __restrict__ X,
                                                      const float* __restrict__ G,
                                                      unsigned short* __restrict__ Y,
                                                      int C, int xs, int ys) {
  int row = blockIdx.x, tid = threadIdx.x;
  __shared__ float xr[1024];
  __shared__ float red[256];
  const float* x = X + (size_t)row * xs;
  float ssq = 0.0f;
  for (int i = tid; i < C; i += 256) { float v = x[i]; xr[i] = v; ssq += v * v; }
  red[tid] = ssq; __syncthreads();
  for (int s = 128; s >= 1; s >>= 1) { if (tid < s) red[tid] += red[tid + s]; __syncthreads(); }
  float inv = 1.0f / sqrtf(red[0] / (float)C + 1e-6f);
  __syncthreads();
  int wv = tid >> 6, lane = tid & 63;
  for (int blk = wv; blk < C / 128; blk += 4) {
    int i0 = blk * 128 + lane, i1 = i0 + 64;
    float y0 = xr[i0] * inv * G[i0];
    float y1 = xr[i1] * inv * G[i1];
    float am = fmaxf(fabsf(y0), fabsf(y1));
#pragma unroll
    for (int m = 32; m >= 1; m >>= 1) am = fmaxf(am, __shfl_xor(am, m, 64));
    am = fmaxf(am, 1e-4f);
    float s = act_scale_from_amax(am);
    Y[(size_t)row * ys + i0] = f32_to_bf16(fp8_e4m3_qdq(clamp448(y0 / s)) * s);
    Y[(size_t)row * ys + i1] = f32_to_bf16(fp8_e4m3_qdq(clamp448(y1 / s)) * s);
  }
}

// ---------------- bf16 MFMA GEMM: C[m,n] (+)= sum_k A[m,k]*B[n,k] (*bs per 128-K) ----------------
// A [4096][K] bf16, B [Npad][K] bf16, tile 128x128, BK=64, 4 waves x (64x64).
template <bool SCALED, bool ACCUM>
__global__ __launch_bounds__(256) void mfma_gemm_kernel(const unsigned short* __restrict__ A,
                                                        const unsigned short* __restrict__ B,
                                                        const float* __restrict__ Bsc,
                                                        float* __restrict__ C,
                                                        int N, int K, int ldc) {
  __shared__ unsigned short lA[128 * 64];
  __shared__ unsigned short lB[128 * 64];
  const int tid = threadIdx.x;
  const int wave = tid >> 6, lane = tid & 63;
  const int wr = (wave >> 1) * 64, wc = (wave & 1) * 64;
  const int m0 = blockIdx.y * 128, n0 = blockIdx.x * 128;
  const int KB = K >> 7;
  const int frow = lane & 15, fk = (lane >> 4) * 8;

  f32x4 mainAcc[4][4];
  f32x4 part[4][4];
  const f32x4 vzero = {0.f, 0.f, 0.f, 0.f};
#pragma unroll
  for (int i = 0; i < 4; ++i)
#pragma unroll
    for (int j = 0; j < 4; ++j) { mainAcc[i][j] = vzero; part[i][j] = vzero; }

  // per-lane LDS byte offset base for staging (wave-uniform base + lane*16 enforced by HW)
  const int nkt = K >> 6;
  for (int kt = 0; kt < nkt; ++kt) {
    const int k0 = kt << 6;
    __syncthreads();
#pragma unroll
    for (int it = 0; it < 4; ++it) {
      int o = it * 4096 + wave * 1024 + lane * 16;  // byte offset within 16KB tile
      int row = o >> 7;                             // 64 bf16 = 128B per row
      int kb = o & 127;
      const char* ga = (const char*)(A + (size_t)(m0 + row) * K + k0) + kb;
      const char* gb = (const char*)(B + (size_t)(n0 + row) * K + k0) + kb;
      __builtin_amdgcn_global_load_lds((gvoid*)ga, (lvoid*)((char*)lA + o), 16, 0, 0);
      __builtin_amdgcn_global_load_lds((gvoid*)gb, (lvoid*)((char*)lB + o), 16, 0, 0);
    }
    __syncthreads();
#pragma unroll
    for (int ks = 0; ks < 2; ++ks) {
      bf16x8 af[4], bfr[4];
#pragma unroll
      for (int i = 0; i < 4; ++i)
        af[i] = *(const bf16x8*)&lA[(wr + i * 16 + frow) * 64 + ks * 32 + fk];
#pragma unroll
      for (int j = 0; j < 4; ++j)
        bfr[j] = *(const bf16x8*)&lB[(wc + j * 16 + frow) * 64 + ks * 32 + fk];
#pragma unroll
      for (int i = 0; i < 4; ++i)
#pragma unroll
        for (int j = 0; j < 4; ++j)
          part[i][j] = __builtin_amdgcn_mfma_f32_16x16x32_bf16(af[i], bfr[j], part[i][j], 0, 0, 0);
    }
    if (SCALED) {
      float bs = Bsc[(size_t)(n0 >> 7) * KB + (k0 >> 7)];
#pragma unroll
      for (int i = 0; i < 4; ++i)
#pragma unroll
        for (int j = 0; j < 4; ++j) {
          mainAcc[i][j] += part[i][j] * bs;
          part[i][j] = vzero;
        }
    }
  }
  const int crow0 = (lane >> 4) * 4;
  const int ccol = lane & 15;
#pragma unroll
  for (int i = 0; i < 4; ++i) {
#pragma unroll
    for (int j = 0; j < 4; ++j) {
      f32x4 v = SCALED ? mainAcc[i][j] : part[i][j];
      int col = n0 + wc + j * 16 + ccol;
      if (col < N) {
#pragma unroll
        for (int r = 0; r < 4; ++r) {
          size_t off = (size_t)(m0 + wr + i * 16 + crow0 + r) * ldc + col;
          C[off] = ACCUM ? (C[off] + v[r]) : v[r];
        }
      }
    }
  }
}

// ---------------- f32 GEMM (kept for tiny Wig) ----------------
template <bool AQ, bool BQ>
__global__ __launch_bounds__(256) void gemm_kernel(const float* __restrict__ A,
                                                   const float* __restrict__ Asc,
                                                   const float* __restrict__ Bw,
                                                   const float* __restrict__ Bsc,
                                                   float* __restrict__ C,
                                                   int N, int K, float alpha) {
  __shared__ __align__(16) float As[16][68];
  __shared__ __align__(16) float Bs[16][68];
  int n0 = blockIdx.x * 64;
  int m0 = blockIdx.y * 64;
  int tid = threadIdx.x;
  int tx = tid & 15, ty = tid >> 4;
  float acc[4][4] = {};
  for (int k0 = 0; k0 < K; k0 += 16) {
#pragma unroll
    for (int t = 0; t < 4; ++t) {
      int idx = tid + t * 256;
      int rr = idx >> 4;
      int kk = idx & 15;
      As[kk][rr] = A[(size_t)(m0 + rr) * K + (k0 + kk)];
      Bs[kk][rr] = (n0 + rr < N) ? Bw[(size_t)(n0 + rr) * K + (k0 + kk)] : 0.0f;
    }
    __syncthreads();
#pragma unroll
    for (int kk = 0; kk < 16; ++kk) {
      float4 a = *(const float4*)&As[kk][ty * 4];
      float4 b = *(const float4*)&Bs[kk][tx * 4];
      float av[4] = {a.x, a.y, a.z, a.w};
      float bv[4] = {b.x, b.y, b.z, b.w};
#pragma unroll
      for (int i = 0; i < 4; ++i)
#pragma unroll
        for (int j = 0; j < 4; ++j) acc[i][j] += av[i] * bv[j];
    }
    __syncthreads();
  }
#pragma unroll
  for (int i = 0; i < 4; ++i) {
    int m = m0 + ty * 4 + i;
#pragma unroll
    for (int j = 0; j < 4; ++j) {
      int n = n0 + tx * 4 + j;
      if (n < N) C[(size_t)m * N + n] = alpha * acc[i][j];
    }
  }
}

// ---------------- RoPE ----------------
__global__ __launch_bounds__(64) void rope_kernel(float* __restrict__ Q,
                                                  const float* __restrict__ KVA,
                                                  float* __restrict__ KR,
                                                  const int* __restrict__ POS) {
  int t = blockIdx.x;
  int tid = threadIdx.x;
  __shared__ float cs[32], sn[32];
  if (tid < 32) {
    int pos = POS[t];
    double inv = pow(10000.0, -((double)(2 * tid) / 64.0));
    float ang = (float)pos * (float)inv;
    cs[tid] = cosf(ang);
    sn[tid] = sinf(ang);
  }
  __syncthreads();
  if (tid < 32) {
    const float* kr = KVA + (size_t)t * (kKvLora + kDR) + kKvLora;
    float x1 = kr[tid], x2 = kr[32 + tid];
    KR[(size_t)t * kDR + tid]      = x1 * cs[tid] - x2 * sn[tid];
    KR[(size_t)t * kDR + 32 + tid] = x2 * cs[tid] + x1 * sn[tid];
  }
  for (int it = tid; it < kH * 32; it += 64) {
    int h = it >> 5, i = it & 31;
    float* qr = Q + ((size_t)t * kH + h) * (kDN + kDR) + kDN;
    float x1 = qr[i], x2 = qr[32 + i];
    qr[i]      = x1 * cs[i] - x2 * sn[i];
    qr[32 + i] = x2 * cs[i] + x1 * sn[i];
  }
}

// ---------------- fused indexer scores + exact stable top-k ----------------
__global__ __launch_bounds__(256) void isc_topk_kernel(const float* __restrict__ QI,
                                                       const float* __restrict__ KI,
                                                       const float* __restrict__ WGT,
                                                       unsigned* __restrict__ SEL) {
  int row = blockIdx.x;
  int q = row & (kS - 1);
  int b = row >> 11;
  int L = q + 1;
  unsigned* selrow = SEL + (size_t)row * (kS / 32);
  int tid = threadIdx.x;
  if (L <= kTopK) {
    if (tid < kS / 32) {
      int base = tid * 32;
      unsigned w;
      if (base + 32 <= L) w = 0xFFFFFFFFu;
      else if (base >= L) w = 0u;
      else w = (1u << (L - base)) - 1u;
      selrow[tid] = w;
    }
    return;
  }
  __shared__ __align__(16) float qrow[kHI * kDI];
  __shared__ float wg[kHI];
  __shared__ unsigned keys[kS];
  __shared__ unsigned hist[256];
  __shared__ unsigned msk[kS / 32];
  __shared__ unsigned pick[2];
  for (int i = tid; i < kHI * kDI; i += 256) qrow[i] = QI[(size_t)row * (kHI * kDI) + i];
  if (tid < kHI) wg[tid] = WGT[(size_t)row * kHI + tid];
  if (tid < kS / 32) msk[tid] = 0u;
  __syncthreads();
  for (int k = tid; k < L; k += 256) {
    const float* kp = KI + (size_t)(b * kS + k) * kDI;
    float d[kHI] = {};
#pragma unroll 4
    for (int i = 0; i < 32; ++i) {
      float4 kv4 = *(const float4*)(kp + i * 4);
#pragma unroll
      for (int h = 0; h < kHI; ++h) {
        float4 q4 = *(const float4*)&qrow[h * kDI + i * 4];
        d[h] += q4.x * kv4.x + q4.y * kv4.y + q4.z * kv4.z + q4.w * kv4.w;
      }
    }
    float sc = 0.0f;
#pragma unroll
    for (int h = 0; h < kHI; ++h) sc += fmaxf(d[h], 0.0f) * wg[h];
    unsigned u = __float_as_uint(sc);
    keys[k] = (u & 0x80000000u) ? ~u : (u | 0x80000000u);
  }
  __syncthreads();
  unsigned prefix = 0u;
  int r = kTopK;
  for (int shift = 24; shift >= 0; shift -= 8) {
    hist[tid] = 0u;
    __syncthreads();
    unsigned hm = (shift == 24) ? 0u : (0xFFFFFFFFu << (shift + 8));
    for (int k = tid; k < L; k += 256) {
      unsigned key = keys[k];
      if ((key & hm) == (prefix & hm)) atomicAdd(&hist[(key >> shift) & 255u], 1u);
    }
    __syncthreads();
    if (tid == 0) {
      int rr = r, bsel = 0;
      for (int bb = 255; bb >= 0; --bb) {
        int c = (int)hist[bb];
        if (rr <= c) { bsel = bb; break; }
        rr -= c;
      }
      pick[0] = (unsigned)bsel;
      pick[1] = (unsigned)rr;
    }
    __syncthreads();
    prefix |= pick[0] << shift;
    r = (int)pick[1];
    __syncthreads();
  }
  unsigned T = prefix;
  int ties_take = r;
  int base = tid * 8;
  int cnt = 0;
#pragma unroll
  for (int j = 0; j < 8; ++j) {
    int k = base + j;
    if (k < L && keys[k] == T) ++cnt;
  }
  hist[tid] = (unsigned)cnt;
  __syncthreads();
  if (tid == 0) {
    unsigned run = 0;
    for (int t = 0; t < 256; ++t) { unsigned c = hist[t]; hist[t] = run; run += c; }
  }
  __syncthreads();
  int trank = (int)hist[tid];
  unsigned bits = 0u;
#pragma unroll
  for (int j = 0; j < 8; ++j) {
    int k = base + j;
    if (k < L) {
      unsigned key = keys[k];
      bool s;
      if (key > T) s = true;
      else if (key == T) { s = trank < ties_take; ++trank; }
      else s = false;
      if (s) bits |= (1u << j);
    }
  }
  atomicOr(&msk[tid >> 2], bits << ((tid & 3) * 8));
  __syncthreads();
  if (tid < kS / 32) selrow[tid] = msk[tid];
}

// ---------------- tiled flash attention (f32) ----------------
__global__ __launch_bounds__(256) void attn_kernel(const float* __restrict__ Q,
                                                   const float* __restrict__ KV,
                                                   const float* __restrict__ KR,
                                                   const unsigned* __restrict__ SEL,
                                                   float* __restrict__ CTX) {
  const int q0 = blockIdx.x * 64;
  const int h  = blockIdx.y;
  const int b  = blockIdx.z;
  const int tid = threadIdx.x;
  const int tq = tid >> 4, tk = tid & 15;
  const float scale = 0.07216878364870323f;  // 1/sqrt(192)

  __shared__ __align__(16) float bufA[2 * 64 * 68];
  __shared__ __align__(16) float Pt[64][68];
  __shared__ unsigned selw[64][2];
  __shared__ float mrow[64], lrow[64], frow[64];
  float (*Qt)[68] = (float(*)[68])bufA;
  float (*Kt)[68] = (float(*)[68])(bufA + 64 * 68);
  float (*Vs)[128] = (float(*)[128])bufA;

  float O[4][8] = {};
  float acc[4][4] = {};
  if (tid < 64) { mrow[tid] = kNeg; lrow[tid] = 0.0f; }

  const int nkt = (q0 >> 6) + 1;
  for (int kt = 0; kt < nkt; ++kt) {
    const int k0 = kt * 64;
    __syncthreads();
    if (tid < 128) {
      int r = tid >> 1, w = tid & 1;
      selw[r][w] = SEL[(size_t)(b * kS + q0 + r) * (kS / 32) + (k0 >> 5) + w];
    }
#pragma unroll
    for (int dc = 0; dc < 3; ++dc) {
      __syncthreads();
#pragma unroll
      for (int t = 0; t < 4; ++t) {
        int task = t * 256 + tid;
        int r = task >> 4, d4 = task & 15;
        int d = dc * 64 + d4 * 4;
        float4 qv = *(const float4*)&Q[(((size_t)(b * kS + q0 + r) * kH) + h) * (kDN + kDR) + d];
        Qt[d4 * 4 + 0][r] = qv.x; Qt[d4 * 4 + 1][r] = qv.y;
        Qt[d4 * 4 + 2][r] = qv.z; Qt[d4 * 4 + 3][r] = qv.w;
        float4 kv4;
        if (dc < 2) {
          kv4 = *(const float4*)&KV[(((size_t)(b * kS + k0 + r) * kH) + h) * (kDN + kDV) + d];
        } else {
          kv4 = *(const float4*)&KR[(size_t)(b * kS + k0 + r) * kDR + d4 * 4];
        }
        Kt[d4 * 4 + 0][r] = kv4.x; Kt[d4 * 4 + 1][r] = kv4.y;
        Kt[d4 * 4 + 2][r] = kv4.z; Kt[d4 * 4 + 3][r] = kv4.w;
      }
      __syncthreads();
#pragma unroll 8
      for (int dl = 0; dl < 64; ++dl) {
        float4 qa = *(const float4*)&Qt[dl][tq * 4];
        float4 kb = *(const float4*)&Kt[dl][tk * 4];
        float av[4] = {qa.x, qa.y, qa.z, qa.w};
        float bv[4] = {kb.x, kb.y, kb.z, kb.w};
#pragma unroll
        for (int i = 0; i < 4; ++i)
#pragma unroll
          for (int j = 0; j < 4; ++j) acc[i][j] += av[i] * bv[j];
      }
    }
#pragma unroll
    for (int i = 0; i < 4; ++i) {
      int r = tq * 4 + i;
#pragma unroll
      for (int j = 0; j < 4; ++j) {
        int c = tk * 4 + j;
        bool bit = (selw[r][c >> 5] >> (c & 31)) & 1u;
        Pt[c][r] = bit ? acc[i][j] * scale : kNeg;
        acc[i][j] = 0.0f;
      }
    }
    __syncthreads();
    {
      int r = tid >> 2, p = tid & 3;
      float mo = mrow[r];
      float tmax = kNeg;
#pragma unroll
      for (int c = p * 16; c < p * 16 + 16; ++c) tmax = fmaxf(tmax, Pt[c][r]);
      tmax = fmaxf(tmax, __shfl_xor(tmax, 1, 64));
      tmax = fmaxf(tmax, __shfl_xor(tmax, 2, 64));
      float mn = fmaxf(mo, tmax);
      float sum = 0.0f;
#pragma unroll
      for (int c = p * 16; c < p * 16 + 16; ++c) {
        float lx = Pt[c][r];
        float pp = (lx < -1e29f) ? 0.0f : expf(lx - mn);
        Pt[c][r] = pp;
        sum += pp;
      }
      sum += __shfl_xor(sum, 1, 64);
      sum += __shfl_xor(sum, 2, 64);
      if (p == 0) {
        float f = expf(mo - mn);
        frow[r] = f;
        lrow[r] = lrow[r] * f + sum;
        mrow[r] = mn;
      }
    }
    __syncthreads();
#pragma unroll
    for (int i = 0; i < 4; ++i) {
      float f = frow[tq * 4 + i];
#pragma unroll
      for (int j = 0; j < 8; ++j) O[i][j] *= f;
    }
#pragma unroll
    for (int t = 0; t < 8; ++t) {
      int task = t * 256 + tid;
      int kr = task >> 5, d4 = task & 31;
      float4 vv = *(const float4*)&KV[(((size_t)(b * kS + k0 + kr) * kH) + h) * (kDN + kDV) + kDN + d4 * 4];
      *(float4*)&Vs[kr][d4 * 4] = vv;
    }
    __syncthreads();
#pragma unroll 4
    for (int c = 0; c < 64; ++c) {
      float4 pa = *(const float4*)&Pt[c][tq * 4];
      float pv[4] = {pa.x, pa.y, pa.z, pa.w};
#pragma unroll
      for (int j = 0; j < 8; ++j) {
        float v = Vs[c][tk + 16 * j];
#pragma unroll
        for (int i = 0; i < 4; ++i) O[i][j] += pv[i] * v;
      }
    }
  }
  __syncthreads();
#pragma unroll
  for (int i = 0; i < 4; ++i) {
    int r = tq * 4 + i;
    float inv = 1.0f / lrow[r];
    size_t base = (size_t)(b * kS + q0 + r) * (kH * kDV) + (size_t)h * kDV;
#pragma unroll
    for (int j = 0; j < 8; ++j) CTX[base + tk + 16 * j] = O[i][j] * inv;
  }
}

extern "C" void kernel_launch(void* const* d_in, const int* in_sizes, int n_in,
                              void* d_out, int out_size, void* d_ws, size_t ws_size,
                              hipStream_t stream) {
  (void)in_sizes; (void)n_in;

  const float* hidden = (const float*)d_in[0];
  const float* Wqa    = (const float*)d_in[1];
  const float* qnw    = (const float*)d_in[2];
  const float* Wqb    = (const float*)d_in[3];
  const float* Wkva   = (const float*)d_in[4];
  const float* kvnw   = (const float*)d_in[5];
  const float* Wkvb   = (const float*)d_in[6];
  const float* Wiq    = (const float*)d_in[7];
  const float* Wik    = (const float*)d_in[8];
  const float* Wig    = (const float*)d_in[9];
  const float* Wo     = (const float*)d_in[10];
  const int*   pos    = (const int*)d_in[11];
  char* ws = (char*)d_ws;
  float* out = (float*)d_out;

  if (ws_size < WS_NEED) {
    fill_kernel<<<dim3((out_size + 255) / 256), dim3(256), 0, stream>>>(out, out_size, 54321.0f);
    return;
  }

  float* scWqa  = (float*)(ws + OFF_SC) + 0;
  float* scWqb  = (float*)(ws + OFF_SC) + 128;
  float* scWkva = (float*)(ws + OFF_SC) + 320;
  float* scWkvb = (float*)(ws + OFF_SC) + 400;
  float* scWo   = (float*)(ws + OFF_SC) + 528;
  unsigned* sel = (unsigned*)(ws + OFF_SEL_B);
  float* wgt    = (float*)(ws + OFF_WGT_B);
  float* krope  = (float*)(ws + OFF_KR_B);
  unsigned short* wo_b = (unsigned short*)(ws + OFF_WOB_B);

  float* qi  = (float*)(ws + P_QI);
  float* ki  = (float*)(ws + P_KI);
  unsigned short* h_hi  = (unsigned short*)(ws + P_HHI);
  unsigned short* h_lo  = (unsigned short*)(ws + P_HLO);
  unsigned short* wiq_h = (unsigned short*)(ws + P_WIQH);
  unsigned short* wiq_l = (unsigned short*)(ws + P_WIQL);
  unsigned short* wik_h = (unsigned short*)(ws + P_WIKH);
  unsigned short* wik_l = (unsigned short*)(ws + P_WIKL);

  float* kvbuf  = (float*)(ws + P_KVBUF);
  unsigned short* qa_b  = (unsigned short*)(ws + P_QAB);
  float* qa_f   = (float*)(ws + P_QAF);
  float* kva    = (float*)(ws + P_KVA);
  unsigned short* hidq_b = (unsigned short*)(ws + P_HIDQ);
  unsigned short* wqa_b  = (unsigned short*)(ws + P_WQAB);
  unsigned short* wqb_b  = (unsigned short*)(ws + P_WQBB);
  unsigned short* wkva_b = (unsigned short*)(ws + P_WKVAB);
  unsigned short* wkvb_b = (unsigned short*)(ws + P_WKVBB);
  unsigned short* ckv_b  = (unsigned short*)(ws + P_CKVB);
  float* ctx    = (float*)(ws + P_CTX);
  unsigned short* ctx_b = (unsigned short*)(ws + P_CTXB);
  float* qbuf   = (float*)(ws + P_QBUF);

  // ---------- Phase A: indexer + top-k ----------
  split_bf16x2_kernel<<<dim3(32768), dim3(256), 0, stream>>>(hidden, h_hi, h_lo, (size_t)kNTok * kDH);
  split_bf16x2_kernel<<<dim3(8192),  dim3(256), 0, stream>>>(Wiq, wiq_h, wiq_l, (size_t)kHI * kDI * kDH);
  split_bf16x2_kernel<<<dim3(1024),  dim3(256), 0, stream>>>(Wik, wik_h, wik_l, (size_t)kDI * kDH);
  gemm_kernel<false, false><<<dim3(1, 64), dim3(256), 0, stream>>>(hidden, nullptr, Wig, nullptr, wgt, kHI, kDH, 0.35355339059327373f);
  // qi = Hhi*Whi + Hhi*Wlo + Hlo*Whi
  mfma_gemm_kernel<false, false><<<dim3(8, 32), dim3(256), 0, stream>>>(h_hi, wiq_h, nullptr, qi, 1024, kDH, 1024);
  mfma_gemm_kernel<false, true ><<<dim3(8, 32), dim3(256), 0, stream>>>(h_hi, wiq_l, nullptr, qi, 1024, kDH, 1024);
  mfma_gemm_kernel<false, true ><<<dim3(8, 32), dim3(256), 0, stream>>>(h_lo, wiq_h, nullptr, qi, 1024, kDH, 1024);
  mfma_gemm_kernel<false, false><<<dim3(1, 32), dim3(256), 0, stream>>>(h_hi, wik_h, nullptr, ki, 128, kDH, 128);
  mfma_gemm_kernel<false, true ><<<dim3(1, 32), dim3(256), 0, stream>>>(h_hi, wik_l, nullptr, ki, 128, kDH, 128);
  mfma_gemm_kernel<false, true ><<<dim3(1, 32), dim3(256), 0, stream>>>(h_lo, wik_h, nullptr, ki, 128, kDH, 128);
  isc_topk_kernel<<<dim3(kNTok), dim3(256), 0, stream>>>(qi, ki, wgt, sel);

  // ---------- Phase B: fp8-path linears on MFMA ----------
  weight_scale_kernel<<<dim3(16, 8),  dim3(256), 0, stream>>>(Wqa,  scWqa,  kQLora, kDH);
  weight_scale_kernel<<<dim3(8, 24),  dim3(256), 0, stream>>>(Wqb,  scWqb,  kH * (kDN + kDR), kQLora);
  weight_scale_kernel<<<dim3(16, 5),  dim3(256), 0, stream>>>(Wkva, scWkva, kKvLora + kDR, kDH);
  weight_scale_kernel<<<dim3(4, 32),  dim3(256), 0, stream>>>(Wkvb, scWkvb, kH * (kDN + kDV), kKvLora);
  weight_scale_kernel<<<dim3(16, 16), dim3(256), 0, stream>>>(Wo,   scWo,   kDH, kH * kDV);
  weight_to_bf16_kernel<<<dim3(8192),  dim3(256), 0, stream>>>(Wqa,  scWqa,  wqa_b,  kQLora, kDH, 1024);
  weight_to_bf16_kernel<<<dim3(12288), dim3(256), 0, stream>>>(Wqb,  scWqb,  wqb_b,  kH * (kDN + kDR), kQLora, 3072);
  weight_to_bf16_kernel<<<dim3(5120),  dim3(256), 0, stream>>>(Wkva, scWkva, wkva_b, kKvLora + kDR, kDH, 640);
  weight_to_bf16_kernel<<<dim3(8192),  dim3(256), 0, stream>>>(Wkvb, scWkvb, wkvb_b, kH * (kDN + kDV), kKvLora, 4096);
  weight_to_bf16_kernel<<<dim3(16384), dim3(256), 0, stream>>>(Wo,   scWo,   wo_b,   kDH, kH * kDV, 2048);
  act_to_bf16_kernel<<<dim3(16384), dim3(256), 0, stream>>>(hidden, hidq_b, kNTok * (kDH / 128));

  mfma_gemm_kernel<true, false><<<dim3(8, 32), dim3(256), 0, stream>>>(hidq_b, wqa_b, scWqa, qa_f, 1024, kDH, 1024);
  rms_qdq_kernel<<<dim3(kNTok), dim3(256), 0, stream>>>(qa_f, qnw, qa_b, kQLora, kQLora, kQLora);
  mfma_gemm_kernel<true, false><<<dim3(24, 32), dim3(256), 0, stream>>>(qa_b, wqb_b, scWqb, qbuf, 3072, kQLora, 3072);
  mfma_gemm_kernel<true, false><<<dim3(5, 32), dim3(256), 0, stream>>>(hidq_b, wkva_b, scWkva, kva, 576, kDH, 576);
  rms_qdq_kernel<<<dim3(kNTok), dim3(256), 0, stream>>>(kva, kvnw, ckv_b, kKvLora, kKvLora + kDR, kKvLora);
  rope_kernel<<<dim3(kNTok), dim3(64), 0, stream>>>(qbuf, kva, krope, pos);
  mfma_gemm_kernel<true, false><<<dim3(32, 32), dim3(256), 0, stream>>>(ckv_b, wkvb_b, scWkvb, kvbuf, 4096, kKvLora, 4096);

  // ---------- attention + output ----------
  attn_kernel<<<dim3(kS / 64, kH, kB), dim3(256), 0, stream>>>(qbuf, kvbuf, krope, sel, ctx);
  act_to_bf16_kernel<<<dim3(16384), dim3(256), 0, stream>>>(ctx, ctx_b, kNTok * ((kH * kDV) / 128));
  mfma_gemm_kernel<true, false><<<dim3(16, 32), dim3(256), 0, stream>>>(ctx_b, wo_b, scWo, out, kDH, kH * kDV, 2048);
}

// Round 6
// 1738.402 us; speedup vs baseline: 15.9633x; 1.5378x over previous
//
#include <hip/hip_runtime.h>
#include <math.h>

namespace {
constexpr int kB = 2, kS = 2048, kDH = 2048, kH = 16, kDN = 128, kDR = 64, kDV = 128;
constexpr int kKvLora = 512, kQLora = 1024, kHI = 8, kDI = 128, kTopK = 1024;
constexpr int kNTok = kB * kS;             // 4096
constexpr float kNeg = -1e30f;

constexpr size_t MB = 1ull << 20;
// ---- fixed region (bytes) ----
constexpr size_t OFF_SC    = 0;                          // 784 f32 scales
constexpr size_t OFF_SEL_B = 4096;                       // 1 MB
constexpr size_t OFF_WGT_B = OFF_SEL_B + 1048576;        // 128 KB
constexpr size_t OFF_KRH_B = OFF_WGT_B + 131072;         // 512 KB
constexpr size_t OFF_KRL_B = OFF_KRH_B + 524288;         // 512 KB
constexpr size_t OFF_WOB_B = OFF_KRL_B + 524288;         // 8 MB  (Wo bf16)
constexpr size_t POOL      = OFF_WOB_B + 8388608;        // 10,620,928
// ---- phase A (indexer) ----
constexpr size_t A_QI   = POOL;                 // 16 MB f32
constexpr size_t A_KI   = POOL + 16 * MB;       // 2 MB f32
constexpr size_t A_HHI  = POOL + 20 * MB;       // 16 MB bf16
constexpr size_t A_HLO  = POOL + 36 * MB;       // 16 MB bf16
constexpr size_t A_WIQH = POOL + 52 * MB;       // 4 MB
constexpr size_t A_WIQL = POOL + 56 * MB;       // 4 MB
constexpr size_t A_WIKH = POOL + 60 * MB;       // 512 KB
constexpr size_t A_WIKL = POOL + 60 * MB + 524288;
// ---- phase B ----
constexpr size_t B_HIDQ = POOL;                 // 16 MB bf16 (dead after kva GEMM)
constexpr size_t B_WQA  = POOL + 16 * MB;       // 4 MB
constexpr size_t B_WQB  = POOL + 20 * MB;       // 6 MB
constexpr size_t B_WKVA = POOL + 26 * MB;       // 2.5 MB
constexpr size_t B_WKVB = POOL + 29884416;      // 4 MB (28.5 MB)
constexpr size_t B_QAF  = POOL + 34078720;      // 16 MB f32 (32.5 MB)
constexpr size_t B_KVA  = POOL + 34078720;      // 9.4 MB f32 (over dead qa_f)
constexpr size_t B_QAB  = POOL + 50855936;      // 8 MB bf16 (48.5 MB)
constexpr size_t B_CKV  = POOL + 50855936;      // 4 MB bf16 (over dead qa_b)
constexpr size_t B_QH   = POOL + 59244544;      // 24 MB bf16 (56.5 MB)
constexpr size_t B_QL   = B_QH + 25165824;      // 24 MB (80.5 MB)
constexpr size_t B_KNH  = POOL;                 // 16 MB (over dead hidq)
constexpr size_t B_KNL  = POOL + 109576192;     // 16 MB (104.5 MB)
constexpr size_t B_VT   = POOL + 126353408;     // 16 MB (120.5 MB)
constexpr size_t B_CTX  = POOL + 16 * MB;       // 32 MB f32
constexpr size_t B_CTXB = POOL + 59244544;      // 16 MB bf16 (over dead Qh)
constexpr size_t WS_NEED = POOL + 143130624;    // ~153.8 MB
} // namespace

typedef __attribute__((ext_vector_type(4))) float f32x4;
typedef __attribute__((ext_vector_type(8))) short bf16x8;
typedef __attribute__((address_space(1))) const void gvoid;
typedef __attribute__((address_space(3))) void lvoid;

// Exact e4m3fn round-to-nearest-even quant-dequant for |x| <= 448 (incl. subnormals).
__device__ __forceinline__ float fp8_e4m3_qdq(float x) {
  float ax = fabsf(x);
  int e;
  (void)frexpf(ax, &e);
  int ee = e - 1;
  if (ee < -6) ee = -6;
  float q = ldexpf(1.0f, ee - 3);
  float y = rintf(ax / q) * q;
  return (x < 0.0f) ? -y : y;
}

__device__ __forceinline__ float act_scale_from_amax(float amax) {
  float t = amax / 448.0f;
  unsigned u = __float_as_uint(t);
  int e = (int)((u >> 23) & 255u) - 127;
  if (u & 0x7fffffu) e += 1;
  return __uint_as_float((unsigned)(e + 127) << 23);
}

__device__ __forceinline__ float clamp448(float v) {
  return fminf(fmaxf(v, -448.0f), 448.0f);
}

__device__ __forceinline__ unsigned short f32_to_bf16(float f) {
  unsigned u = __float_as_uint(f);
  unsigned r = (u + 0x7FFFu + ((u >> 16) & 1u)) >> 16;
  return (unsigned short)r;
}
__device__ __forceinline__ float bf16_to_f32(unsigned short h) {
  return __uint_as_float((unsigned)h << 16);
}

__global__ __launch_bounds__(256) void fill_kernel(float* p, int n, float v) {
  int i = blockIdx.x * 256 + threadIdx.x;
  if (i < n) p[i] = v;
}

// ---------------- weight 128x128-block scale ----------------
__global__ __launch_bounds__(256) void weight_scale_kernel(const float* __restrict__ W,
                                                           float* __restrict__ SC, int O, int I) {
  int kb = blockIdx.x, ob = blockIdx.y;
  int bo = ob * 128, bi = kb * 128;
  int tid = threadIdx.x;
  __shared__ float red[256];
  float am = 0.0f;
  for (int idx = tid; idx < 128 * 128; idx += 256) {
    int r = bo + (idx >> 7), c = bi + (idx & 127);
    if (r < O) am = fmaxf(am, fabsf(W[(size_t)r * I + c]));
  }
  red[tid] = am; __syncthreads();
  for (int s = 128; s >= 1; s >>= 1) {
    if (tid < s) red[tid] = fmaxf(red[tid], red[tid + s]);
    __syncthreads();
  }
  if (tid == 0) SC[(size_t)ob * gridDim.x + kb] = fmaxf(red[0], 1e-4f) / 448.0f;
}

// ---------------- weight -> bf16 quantized values (no scale applied) ----------------
__global__ __launch_bounds__(256) void weight_to_bf16_kernel(const float* __restrict__ W,
                                                             const float* __restrict__ SC,
                                                             unsigned short* __restrict__ WB,
                                                             int O, int I, int Opad) {
  size_t idx = (size_t)blockIdx.x * 256 + threadIdx.x;
  if (idx >= (size_t)Opad * I) return;
  int r = (int)(idx / I), c = (int)(idx % I);
  unsigned short v = 0;
  if (r < O) {
    float s = SC[(size_t)(r >> 7) * (I >> 7) + (c >> 7)];
    float q = fp8_e4m3_qdq(clamp448(W[(size_t)r * I + c] / s));
    v = f32_to_bf16(q);  // exact: e4m3 values fit bf16
  }
  WB[idx] = v;
}

// ---------------- activation qdq -> bf16 (per 128-block pow2 scale; exact) ----------------
__global__ __launch_bounds__(256) void act_to_bf16_kernel(const float* __restrict__ X,
                                                          unsigned short* __restrict__ Y, int nblk) {
  int wid = blockIdx.x * 4 + (threadIdx.x >> 6);
  int lane = threadIdx.x & 63;
  if (wid >= nblk) return;
  const float* x = X + (size_t)wid * 128;
  float v0 = x[lane], v1 = x[lane + 64];
  float am = fmaxf(fabsf(v0), fabsf(v1));
#pragma unroll
  for (int m = 32; m >= 1; m >>= 1) am = fmaxf(am, __shfl_xor(am, m, 64));
  am = fmaxf(am, 1e-4f);
  float s = act_scale_from_amax(am);
  Y[(size_t)wid * 128 + lane]      = f32_to_bf16(fp8_e4m3_qdq(clamp448(v0 / s)) * s);
  Y[(size_t)wid * 128 + 64 + lane] = f32_to_bf16(fp8_e4m3_qdq(clamp448(v1 / s)) * s);
}

// ---------------- f32 -> bf16 hi/lo split ----------------
__global__ __launch_bounds__(256) void split_bf16x2_kernel(const float* __restrict__ X,
                                                           unsigned short* __restrict__ HI,
                                                           unsigned short* __restrict__ LO,
                                                           size_t n) {
  size_t i = (size_t)blockIdx.x * 256 + threadIdx.x;
  if (i >= n) return;
  float x = X[i];
  unsigned short h = f32_to_bf16(x);
  HI[i] = h;
  LO[i] = f32_to_bf16(x - bf16_to_f32(h));
}

// ---------------- fused RMSNorm + activation qdq -> bf16 (per row) ----------------
__global__ __launch_bounds__(256) void rms_qdq_kernel(const float* __restrict__ X,
                                                      const float* __restrict__ G,
                                                      unsigned short* __restrict__ Y,
                                                      int C, int xs, int ys) {
  int row = blockIdx.x, tid = threadIdx.x;
  __shared__ float xr[1024];
  __shared__ float red[256];
  const float* x = X + (size_t)row * xs;
  float ssq = 0.0f;
  for (int i = tid; i < C; i += 256) { float v = x[i]; xr[i] = v; ssq += v * v; }
  red[tid] = ssq; __syncthreads();
  for (int s = 128; s >= 1; s >>= 1) { if (tid < s) red[tid] += red[tid + s]; __syncthreads(); }
  float inv = 1.0f / sqrtf(red[0] / (float)C + 1e-6f);
  __syncthreads();
  int wv = tid >> 6, lane = tid & 63;
  for (int blk = wv; blk < C / 128; blk += 4) {
    int i0 = blk * 128 + lane, i1 = i0 + 64;
    float y0 = xr[i0] * inv * G[i0];
    float y1 = xr[i1] * inv * G[i1];
    float am = fmaxf(fabsf(y0), fabsf(y1));
#pragma unroll
    for (int m = 32; m >= 1; m >>= 1) am = fmaxf(am, __shfl_xor(am, m, 64));
    am = fmaxf(am, 1e-4f);
    float s = act_scale_from_amax(am);
    Y[(size_t)row * ys + i0] = f32_to_bf16(fp8_e4m3_qdq(clamp448(y0 / s)) * s);
    Y[(size_t)row * ys + i1] = f32_to_bf16(fp8_e4m3_qdq(clamp448(y1 / s)) * s);
  }
}

// ---------------- bf16 MFMA GEMM, templated epilogue ----------------
// C[m,n] = sum_k A[m,k]*B[n,k] (* per-128K block scale if SCALED).  M = 4096.
// OMODE 0: f32 C (ACCUM optional).
// OMODE 1: bf16 hi/lo pair (O1,O2) in [b,h,s,192]: col=(h*192+d), m=(b*2048+s).
// OMODE 2: kv-split: col=(h<<8)+d; d<128 -> Knh/Knl[((b*16+h)*2048+s)*128+d];
//          d>=128 -> Vt[((b*16+h)*128+(d-128))*2048+s]  (b=m>>11, s=m&2047).
template <int OMODE, bool SCALED, bool ACCUM>
__global__ __launch_bounds__(256) void mfma_gemm_kernel(const unsigned short* __restrict__ A,
                                                        const unsigned short* __restrict__ B,
                                                        const float* __restrict__ Bsc,
                                                        float* __restrict__ C,
                                                        unsigned short* __restrict__ O1,
                                                        unsigned short* __restrict__ O2,
                                                        unsigned short* __restrict__ O3,
                                                        int N, int K, int ldc) {
  __shared__ unsigned short lA[128 * 64];
  __shared__ unsigned short lB[128 * 64];
  const int tid = threadIdx.x;
  const int wave = tid >> 6, lane = tid & 63;
  const int wr = (wave >> 1) * 64, wc = (wave & 1) * 64;
  const int m0 = blockIdx.y * 128, n0 = blockIdx.x * 128;
  const int KB = K >> 7;
  const int frow = lane & 15, fk = (lane >> 4) * 8;

  f32x4 mainAcc[4][4];
  f32x4 part[4][4];
  const f32x4 vzero = {0.f, 0.f, 0.f, 0.f};
#pragma unroll
  for (int i = 0; i < 4; ++i)
#pragma unroll
    for (int j = 0; j < 4; ++j) { mainAcc[i][j] = vzero; part[i][j] = vzero; }

  const int nkt = K >> 6;
  for (int kt = 0; kt < nkt; ++kt) {
    const int k0 = kt << 6;
    __syncthreads();
#pragma unroll
    for (int it = 0; it < 4; ++it) {
      int o = it * 4096 + wave * 1024 + lane * 16;
      int row = o >> 7;
      int kb = o & 127;
      const char* ga = (const char*)(A + (size_t)(m0 + row) * K + k0) + kb;
      const char* gb = (const char*)(B + (size_t)(n0 + row) * K + k0) + kb;
      __builtin_amdgcn_global_load_lds((gvoid*)ga, (lvoid*)((char*)lA + o), 16, 0, 0);
      __builtin_amdgcn_global_load_lds((gvoid*)gb, (lvoid*)((char*)lB + o), 16, 0, 0);
    }
    __syncthreads();
#pragma unroll
    for (int ks = 0; ks < 2; ++ks) {
      bf16x8 af[4], bfr[4];
#pragma unroll
      for (int i = 0; i < 4; ++i)
        af[i] = *(const bf16x8*)&lA[(wr + i * 16 + frow) * 64 + ks * 32 + fk];
#pragma unroll
      for (int j = 0; j < 4; ++j)
        bfr[j] = *(const bf16x8*)&lB[(wc + j * 16 + frow) * 64 + ks * 32 + fk];
#pragma unroll
      for (int i = 0; i < 4; ++i)
#pragma unroll
        for (int j = 0; j < 4; ++j)
          part[i][j] = __builtin_amdgcn_mfma_f32_16x16x32_bf16(af[i], bfr[j], part[i][j], 0, 0, 0);
    }
    if (SCALED) {
      float bs = Bsc[(size_t)(n0 >> 7) * KB + (k0 >> 7)];
#pragma unroll
      for (int i = 0; i < 4; ++i)
#pragma unroll
        for (int j = 0; j < 4; ++j) {
          mainAcc[i][j] += part[i][j] * bs;
          part[i][j] = vzero;
        }
    }
  }
  const int crow0 = (lane >> 4) * 4;
  const int ccol = lane & 15;
#pragma unroll
  for (int i = 0; i < 4; ++i) {
#pragma unroll
    for (int j = 0; j < 4; ++j) {
      f32x4 v = SCALED ? mainAcc[i][j] : part[i][j];
      int col = n0 + wc + j * 16 + ccol;
      if (col < N) {
#pragma unroll
        for (int r = 0; r < 4; ++r) {
          int m = m0 + wr + i * 16 + crow0 + r;
          float val = v[r];
          if (OMODE == 0) {
            size_t off = (size_t)m * ldc + col;
            C[off] = ACCUM ? (C[off] + val) : val;
          } else if (OMODE == 1) {
            // [b,h,s,192] layout (matches rope_split + attn readers)
            int hh = col / 192, d = col - hh * 192;
            int bb = m >> 11, s = m & 2047;
            size_t off = ((size_t)((bb * 16 + hh) * 2048 + s)) * 192 + d;
            unsigned short hi = f32_to_bf16(val);
            O1[off] = hi;
            O2[off] = f32_to_bf16(val - bf16_to_f32(hi));
          } else {
            int hh = col >> 8, d = col & 255;
            int bb = m >> 11, s = m & 2047;
            if (d < 128) {
              size_t off = ((size_t)((bb * 16 + hh) * 2048 + s)) * 128 + d;
              unsigned short hi = f32_to_bf16(val);
              O1[off] = hi;
              O2[off] = f32_to_bf16(val - bf16_to_f32(hi));
            } else {
              size_t off = ((size_t)((bb * 16 + hh) * 128 + (d - 128))) * 2048 + s;
              O3[off] = f32_to_bf16(val);
            }
          }
        }
      }
    }
  }
}

// ---------------- f32 GEMM (tiny Wig only) ----------------
__global__ __launch_bounds__(256) void gemm_f32_kernel(const float* __restrict__ A,
                                                       const float* __restrict__ Bw,
                                                       float* __restrict__ C,
                                                       int N, int K, float alpha) {
  __shared__ __align__(16) float As[16][68];
  __shared__ __align__(16) float Bs[16][68];
  int n0 = blockIdx.x * 64;
  int m0 = blockIdx.y * 64;
  int tid = threadIdx.x;
  int tx = tid & 15, ty = tid >> 4;
  float acc[4][4] = {};
  for (int k0 = 0; k0 < K; k0 += 16) {
#pragma unroll
    for (int t = 0; t < 4; ++t) {
      int idx = tid + t * 256;
      int rr = idx >> 4;
      int kk = idx & 15;
      As[kk][rr] = A[(size_t)(m0 + rr) * K + (k0 + kk)];
      Bs[kk][rr] = (n0 + rr < N) ? Bw[(size_t)(n0 + rr) * K + (k0 + kk)] : 0.0f;
    }
    __syncthreads();
#pragma unroll
    for (int kk = 0; kk < 16; ++kk) {
      float4 a = *(const float4*)&As[kk][ty * 4];
      float4 b = *(const float4*)&Bs[kk][tx * 4];
      float av[4] = {a.x, a.y, a.z, a.w};
      float bv[4] = {b.x, b.y, b.z, b.w};
#pragma unroll
      for (int i = 0; i < 4; ++i)
#pragma unroll
        for (int j = 0; j < 4; ++j) acc[i][j] += av[i] * bv[j];
    }
    __syncthreads();
  }
#pragma unroll
  for (int i = 0; i < 4; ++i) {
    int m = m0 + ty * 4 + i;
#pragma unroll
    for (int j = 0; j < 4; ++j) {
      int n = n0 + tx * 4 + j;
      if (n < N) C[(size_t)m * N + n] = alpha * acc[i][j];
    }
  }
}

// ---------------- RoPE on split Q (in place, [b,h,s,192]) + k_rope -> Krh/Krl ----------------
__global__ __launch_bounds__(64) void rope_split_kernel(unsigned short* __restrict__ Qh,
                                                        unsigned short* __restrict__ Ql,
                                                        const float* __restrict__ KVA,
                                                        unsigned short* __restrict__ Krh,
                                                        unsigned short* __restrict__ Krl,
                                                        const int* __restrict__ POS) {
  int t = blockIdx.x;  // b*S + s
  int tid = threadIdx.x;
  int b = t >> 11, s = t & 2047;
  __shared__ float cs[32], sn[32];
  if (tid < 32) {
    int pos = POS[t];
    double inv = pow(10000.0, -((double)(2 * tid) / 64.0));
    float ang = (float)pos * (float)inv;
    cs[tid] = cosf(ang);
    sn[tid] = sinf(ang);
  }
  __syncthreads();
  if (tid < 32) {
    const float* kr = KVA + (size_t)t * (kKvLora + kDR) + kKvLora;
    float x1 = kr[tid], x2 = kr[32 + tid];
    float y1 = x1 * cs[tid] - x2 * sn[tid];
    float y2 = x2 * cs[tid] + x1 * sn[tid];
    unsigned short h1 = f32_to_bf16(y1);
    Krh[(size_t)t * 64 + tid] = h1;
    Krl[(size_t)t * 64 + tid] = f32_to_bf16(y1 - bf16_to_f32(h1));
    unsigned short h2 = f32_to_bf16(y2);
    Krh[(size_t)t * 64 + 32 + tid] = h2;
    Krl[(size_t)t * 64 + 32 + tid] = f32_to_bf16(y2 - bf16_to_f32(h2));
  }
  for (int it = tid; it < kH * 32; it += 64) {
    int h = it >> 5, i = it & 31;
    size_t base = ((size_t)((b * 16 + h) * 2048 + s)) * 192 + 128;
    float x1 = bf16_to_f32(Qh[base + i]) + bf16_to_f32(Ql[base + i]);
    float x2 = bf16_to_f32(Qh[base + 32 + i]) + bf16_to_f32(Ql[base + 32 + i]);
    float y1 = x1 * cs[i] - x2 * sn[i];
    float y2 = x2 * cs[i] + x1 * sn[i];
    unsigned short h1 = f32_to_bf16(y1);
    Qh[base + i] = h1;
    Ql[base + i] = f32_to_bf16(y1 - bf16_to_f32(h1));
    unsigned short h2 = f32_to_bf16(y2);
    Qh[base + 32 + i] = h2;
    Ql[base + 32 + i] = f32_to_bf16(y2 - bf16_to_f32(h2));
  }
}

// ---------------- fused indexer scores + exact stable top-k ----------------
__global__ __launch_bounds__(256) void isc_topk_kernel(const float* __restrict__ QI,
                                                       const float* __restrict__ KI,
                                                       const float* __restrict__ WGT,
                                                       unsigned* __restrict__ SEL) {
  int row = blockIdx.x;
  int q = row & (kS - 1);
  int b = row >> 11;
  int L = q + 1;
  unsigned* selrow = SEL + (size_t)row * (kS / 32);
  int tid = threadIdx.x;
  if (L <= kTopK) {
    if (tid < kS / 32) {
      int base = tid * 32;
      unsigned w;
      if (base + 32 <= L) w = 0xFFFFFFFFu;
      else if (base >= L) w = 0u;
      else w = (1u << (L - base)) - 1u;
      selrow[tid] = w;
    }
    return;
  }
  __shared__ __align__(16) float qrow[kHI * kDI];
  __shared__ float wg[kHI];
  __shared__ unsigned keys[kS];
  __shared__ unsigned hist[256];
  __shared__ unsigned msk[kS / 32];
  __shared__ unsigned pick[2];
  for (int i = tid; i < kHI * kDI; i += 256) qrow[i] = QI[(size_t)row * (kHI * kDI) + i];
  if (tid < kHI) wg[tid] = WGT[(size_t)row * kHI + tid];
  if (tid < kS / 32) msk[tid] = 0u;
  __syncthreads();
  for (int k = tid; k < L; k += 256) {
    const float* kp = KI + (size_t)(b * kS + k) * kDI;
    float d[kHI] = {};
#pragma unroll 4
    for (int i = 0; i < 32; ++i) {
      float4 kv4 = *(const float4*)(kp + i * 4);
#pragma unroll
      for (int h = 0; h < kHI; ++h) {
        float4 q4 = *(const float4*)&qrow[h * kDI + i * 4];
        d[h] += q4.x * kv4.x + q4.y * kv4.y + q4.z * kv4.z + q4.w * kv4.w;
      }
    }
    float sc = 0.0f;
#pragma unroll
    for (int h = 0; h < kHI; ++h) sc += fmaxf(d[h], 0.0f) * wg[h];
    unsigned u = __float_as_uint(sc);
    keys[k] = (u & 0x80000000u) ? ~u : (u | 0x80000000u);
  }
  __syncthreads();
  unsigned prefix = 0u;
  int r = kTopK;
  for (int shift = 24; shift >= 0; shift -= 8) {
    hist[tid] = 0u;
    __syncthreads();
    unsigned hm = (shift == 24) ? 0u : (0xFFFFFFFFu << (shift + 8));
    for (int k = tid; k < L; k += 256) {
      unsigned key = keys[k];
      if ((key & hm) == (prefix & hm)) atomicAdd(&hist[(key >> shift) & 255u], 1u);
    }
    __syncthreads();
    if (tid == 0) {
      int rr = r, bsel = 0;
      for (int bb = 255; bb >= 0; --bb) {
        int c = (int)hist[bb];
        if (rr <= c) { bsel = bb; break; }
        rr -= c;
      }
      pick[0] = (unsigned)bsel;
      pick[1] = (unsigned)rr;
    }
    __syncthreads();
    prefix |= pick[0] << shift;
    r = (int)pick[1];
    __syncthreads();
  }
  unsigned T = prefix;
  int ties_take = r;
  int base = tid * 8;
  int cnt = 0;
#pragma unroll
  for (int j = 0; j < 8; ++j) {
    int k = base + j;
    if (k < L && keys[k] == T) ++cnt;
  }
  hist[tid] = (unsigned)cnt;
  __syncthreads();
  if (tid == 0) {
    unsigned run = 0;
    for (int t = 0; t < 256; ++t) { unsigned c = hist[t]; hist[t] = run; run += c; }
  }
  __syncthreads();
  int trank = (int)hist[tid];
  unsigned bits = 0u;
#pragma unroll
  for (int j = 0; j < 8; ++j) {
    int k = base + j;
    if (k < L) {
      unsigned key = keys[k];
      bool s;
      if (key > T) s = true;
      else if (key == T) { s = trank < ties_take; ++trank; }
      else s = false;
      if (s) bits |= (1u << j);
    }
  }
  atomicOr(&msk[tid >> 2], bits << ((tid & 3) * 8));
  __syncthreads();
  if (tid < kS / 32) selrow[tid] = msk[tid];
}

// ---------------- MFMA flash attention ----------------
// block = (64-q tile, h, b); 4 waves x 16 q-rows. QK^T: 3-pass hi/lo; PV: P hi/lo x V.
__global__ __launch_bounds__(256) void attn_mfma_kernel(const unsigned short* __restrict__ Qh,
                                                        const unsigned short* __restrict__ Ql,
                                                        const unsigned short* __restrict__ Knh,
                                                        const unsigned short* __restrict__ Knl,
                                                        const unsigned short* __restrict__ Krh,
                                                        const unsigned short* __restrict__ Krl,
                                                        const unsigned short* __restrict__ Vt,
                                                        const unsigned* __restrict__ SEL,
                                                        float* __restrict__ CTX) {
  const int q0 = blockIdx.x * 64, h = blockIdx.y, b = blockIdx.z;
  const int tid = threadIdx.x, wave = tid >> 6, lane = tid & 63;
  const int fr = lane & 15, fg = lane >> 4;
  const float scale = 0.07216878364870323f;  // 1/sqrt(192)

  __shared__ unsigned short KsH[64 * 40], KsL[64 * 40];   // K chunk, pad-40 rows
  __shared__ unsigned short Ph[64 * 72], Pl[64 * 72];     // P, pad-72 rows
  __shared__ unsigned short Vs[128 * 72];                 // V^T tile, pad-72 rows
  __shared__ unsigned selw[64][2];

  // Q fragments in registers: row = fr of wave's 16, k = kc*32 + fg*8
  bf16x8 qh[6], ql[6];
  {
    const size_t qbase = ((size_t)((b * 16 + h) * 2048 + q0 + wave * 16 + fr)) * 192;
#pragma unroll
    for (int kc = 0; kc < 6; ++kc) {
      qh[kc] = *(const bf16x8*)&Qh[qbase + kc * 32 + fg * 8];
      ql[kc] = *(const bf16x8*)&Ql[qbase + kc * 32 + fg * 8];
    }
  }
  float m_run[4], l_run[4];
#pragma unroll
  for (int r = 0; r < 4; ++r) { m_run[r] = kNeg; l_run[r] = 0.0f; }
  f32x4 O[8];
  const f32x4 vzero = {0.f, 0.f, 0.f, 0.f};
#pragma unroll
  for (int j = 0; j < 8; ++j) O[j] = vzero;

  const int nkt = (q0 >> 6) + 1;
  for (int kt = 0; kt < nkt; ++kt) {
    const int k0 = kt * 64;
    __syncthreads();  // prev tile fully consumed
    if (tid < 128) {
      int r = tid >> 1, w = tid & 1;
      selw[r][w] = SEL[(size_t)(b * kS + q0 + r) * (kS / 32) + (k0 >> 5) + w];
    }
    // ---- S = Q K^T over 6 32-dim chunks ----
    f32x4 acc[4];
#pragma unroll
    for (int j = 0; j < 4; ++j) acc[j] = vzero;
    for (int kc = 0; kc < 6; ++kc) {
      int key = tid >> 2, sub = (tid & 3) * 8;
      bf16x8 vh, vl;
      if (kc < 4) {
        size_t src = ((size_t)((b * 16 + h) * 2048 + k0 + key)) * 128 + kc * 32 + sub;
        vh = *(const bf16x8*)&Knh[src];
        vl = *(const bf16x8*)&Knl[src];
      } else {
        size_t src = (size_t)(b * kS + k0 + key) * 64 + (kc - 4) * 32 + sub;
        vh = *(const bf16x8*)&Krh[src];
        vl = *(const bf16x8*)&Krl[src];
      }
      __syncthreads();  // prev chunk MFMAs done
      *(bf16x8*)&KsH[key * 40 + sub] = vh;
      *(bf16x8*)&KsL[key * 40 + sub] = vl;
      __syncthreads();
#pragma unroll
      for (int j = 0; j < 4; ++j) {
        bf16x8 kh = *(const bf16x8*)&KsH[(j * 16 + fr) * 40 + fg * 8];
        bf16x8 kl = *(const bf16x8*)&KsL[(j * 16 + fr) * 40 + fg * 8];
        acc[j] = __builtin_amdgcn_mfma_f32_16x16x32_bf16(qh[kc], kh, acc[j], 0, 0, 0);
        acc[j] = __builtin_amdgcn_mfma_f32_16x16x32_bf16(qh[kc], kl, acc[j], 0, 0, 0);
        acc[j] = __builtin_amdgcn_mfma_f32_16x16x32_bf16(ql[kc], kh, acc[j], 0, 0, 0);
      }
    }
    // ---- mask + online softmax (registers; rows = wave*16 + fg*4 + r) ----
    float p[4][4];   // [j][r]
    float fsc[4];
#pragma unroll
    for (int r = 0; r < 4; ++r) {
      int row = wave * 16 + fg * 4 + r;
      float sv[4];
      float vmax = kNeg;
#pragma unroll
      for (int j = 0; j < 4; ++j) {
        int col = j * 16 + fr;
        bool bit = (selw[row][col >> 5] >> (col & 31)) & 1u;
        float s = bit ? acc[j][r] * scale : kNeg;
        sv[j] = s;
        vmax = fmaxf(vmax, s);
      }
#pragma unroll
      for (int m = 1; m <= 8; m <<= 1) vmax = fmaxf(vmax, __shfl_xor(vmax, m, 64));
      float newm = fmaxf(m_run[r], vmax);
      float sum = 0.0f;
#pragma unroll
      for (int j = 0; j < 4; ++j) {
        float pp = (sv[j] < -1e29f) ? 0.0f : expf(sv[j] - newm);
        p[j][r] = pp;
        sum += pp;
      }
#pragma unroll
      for (int m = 1; m <= 8; m <<= 1) sum += __shfl_xor(sum, m, 64);
      fsc[r] = expf(m_run[r] - newm);   // both kNeg -> exp(0)=1
      l_run[r] = l_run[r] * fsc[r] + sum;
      m_run[r] = newm;
    }
    // ---- rescale O; write P hi/lo; stage V^T tile ----
#pragma unroll
    for (int j = 0; j < 8; ++j)
#pragma unroll
      for (int r = 0; r < 4; ++r) O[j][r] *= fsc[r];
#pragma unroll
    for (int r = 0; r < 4; ++r) {
      int row = wave * 16 + fg * 4 + r;
#pragma unroll
      for (int j = 0; j < 4; ++j) {
        int col = j * 16 + fr;
        float pp = p[j][r];
        unsigned short hi = f32_to_bf16(pp);
        Ph[row * 72 + col] = hi;
        Pl[row * 72 + col] = f32_to_bf16(pp - bf16_to_f32(hi));
      }
    }
    {
      const size_t vbase = ((size_t)((b * 16 + h) * 128)) * 2048 + k0;
#pragma unroll
      for (int it = 0; it < 4; ++it) {
        int idx = it * 256 + tid;
        int dv = idx >> 3, ks8 = (idx & 7) * 8;
        bf16x8 vv = *(const bf16x8*)&Vt[vbase + (size_t)dv * 2048 + ks8];
        *(bf16x8*)&Vs[dv * 72 + ks8] = vv;
      }
    }
    __syncthreads();
    // ---- PV: O += P * V ----
#pragma unroll
    for (int kk = 0; kk < 2; ++kk) {
      bf16x8 pah = *(const bf16x8*)&Ph[(wave * 16 + fr) * 72 + kk * 32 + fg * 8];
      bf16x8 pal = *(const bf16x8*)&Pl[(wave * 16 + fr) * 72 + kk * 32 + fg * 8];
#pragma unroll
      for (int j = 0; j < 8; ++j) {
        bf16x8 vb = *(const bf16x8*)&Vs[(j * 16 + fr) * 72 + kk * 32 + fg * 8];
        O[j] = __builtin_amdgcn_mfma_f32_16x16x32_bf16(pah, vb, O[j], 0, 0, 0);
        O[j] = __builtin_amdgcn_mfma_f32_16x16x32_bf16(pal, vb, O[j], 0, 0, 0);
      }
    }
  }
  // ---- normalize + write ctx [b*S+s][h*128+dv] ----
#pragma unroll
  for (int r = 0; r < 4; ++r) {
    float inv = 1.0f / l_run[r];
    size_t obase = (size_t)(b * kS + q0 + wave * 16 + fg * 4 + r) * 2048 + h * 128;
#pragma unroll
    for (int j = 0; j < 8; ++j) CTX[obase + j * 16 + fr] = O[j][r] * inv;
  }
}

extern "C" void kernel_launch(void* const* d_in, const int* in_sizes, int n_in,
                              void* d_out, int out_size, void* d_ws, size_t ws_size,
                              hipStream_t stream) {
  (void)in_sizes; (void)n_in;

  const float* hidden = (const float*)d_in[0];
  const float* Wqa    = (const float*)d_in[1];
  const float* qnw    = (const float*)d_in[2];
  const float* Wqb    = (const float*)d_in[3];
  const float* Wkva   = (const float*)d_in[4];
  const float* kvnw   = (const float*)d_in[5];
  const float* Wkvb   = (const float*)d_in[6];
  const float* Wiq    = (const float*)d_in[7];
  const float* Wik    = (const float*)d_in[8];
  const float* Wig    = (const float*)d_in[9];
  const float* Wo     = (const float*)d_in[10];
  const int*   pos    = (const int*)d_in[11];
  char* ws = (char*)d_ws;
  float* out = (float*)d_out;

  if (ws_size < WS_NEED) {
    fill_kernel<<<dim3((out_size + 255) / 256), dim3(256), 0, stream>>>(out, out_size, 54321.0f);
    return;
  }

  float* scWqa  = (float*)(ws + OFF_SC) + 0;
  float* scWqb  = (float*)(ws + OFF_SC) + 128;
  float* scWkva = (float*)(ws + OFF_SC) + 320;
  float* scWkvb = (float*)(ws + OFF_SC) + 400;
  float* scWo   = (float*)(ws + OFF_SC) + 528;
  unsigned* sel = (unsigned*)(ws + OFF_SEL_B);
  float* wgt    = (float*)(ws + OFF_WGT_B);
  unsigned short* krh = (unsigned short*)(ws + OFF_KRH_B);
  unsigned short* krl = (unsigned short*)(ws + OFF_KRL_B);
  unsigned short* wo_b = (unsigned short*)(ws + OFF_WOB_B);

  float* qi  = (float*)(ws + A_QI);
  float* ki  = (float*)(ws + A_KI);
  unsigned short* h_hi  = (unsigned short*)(ws + A_HHI);
  unsigned short* h_lo  = (unsigned short*)(ws + A_HLO);
  unsigned short* wiq_h = (unsigned short*)(ws + A_WIQH);
  unsigned short* wiq_l = (unsigned short*)(ws + A_WIQL);
  unsigned short* wik_h = (unsigned short*)(ws + A_WIKH);
  unsigned short* wik_l = (unsigned short*)(ws + A_WIKL);

  unsigned short* hidq_b = (unsigned short*)(ws + B_HIDQ);
  unsigned short* wqa_b  = (unsigned short*)(ws + B_WQA);
  unsigned short* wqb_b  = (unsigned short*)(ws + B_WQB);
  unsigned short* wkva_b = (unsigned short*)(ws + B_WKVA);
  unsigned short* wkvb_b = (unsigned short*)(ws + B_WKVB);
  float* qa_f   = (float*)(ws + B_QAF);
  float* kva    = (float*)(ws + B_KVA);
  unsigned short* qa_b  = (unsigned short*)(ws + B_QAB);
  unsigned short* ckv_b = (unsigned short*)(ws + B_CKV);
  unsigned short* q_h   = (unsigned short*)(ws + B_QH);
  unsigned short* q_l   = (unsigned short*)(ws + B_QL);
  unsigned short* kn_h  = (unsigned short*)(ws + B_KNH);
  unsigned short* kn_l  = (unsigned short*)(ws + B_KNL);
  unsigned short* v_t   = (unsigned short*)(ws + B_VT);
  float* ctx    = (float*)(ws + B_CTX);
  unsigned short* ctx_b = (unsigned short*)(ws + B_CTXB);

  // ---------- Phase A: indexer + top-k ----------
  split_bf16x2_kernel<<<dim3(32768), dim3(256), 0, stream>>>(hidden, h_hi, h_lo, (size_t)kNTok * kDH);
  split_bf16x2_kernel<<<dim3(8192),  dim3(256), 0, stream>>>(Wiq, wiq_h, wiq_l, (size_t)kHI * kDI * kDH);
  split_bf16x2_kernel<<<dim3(1024),  dim3(256), 0, stream>>>(Wik, wik_h, wik_l, (size_t)kDI * kDH);
  gemm_f32_kernel<<<dim3(1, 64), dim3(256), 0, stream>>>(hidden, Wig, wgt, kHI, kDH, 0.35355339059327373f);
  mfma_gemm_kernel<0, false, false><<<dim3(8, 32), dim3(256), 0, stream>>>(h_hi, wiq_h, nullptr, qi, nullptr, nullptr, nullptr, 1024, kDH, 1024);
  mfma_gemm_kernel<0, false, true ><<<dim3(8, 32), dim3(256), 0, stream>>>(h_hi, wiq_l, nullptr, qi, nullptr, nullptr, nullptr, 1024, kDH, 1024);
  mfma_gemm_kernel<0, false, true ><<<dim3(8, 32), dim3(256), 0, stream>>>(h_lo, wiq_h, nullptr, qi, nullptr, nullptr, nullptr, 1024, kDH, 1024);
  mfma_gemm_kernel<0, false, false><<<dim3(1, 32), dim3(256), 0, stream>>>(h_hi, wik_h, nullptr, ki, nullptr, nullptr, nullptr, 128, kDH, 128);
  mfma_gemm_kernel<0, false, true ><<<dim3(1, 32), dim3(256), 0, stream>>>(h_hi, wik_l, nullptr, ki, nullptr, nullptr, nullptr, 128, kDH, 128);
  mfma_gemm_kernel<0, false, true ><<<dim3(1, 32), dim3(256), 0, stream>>>(h_lo, wik_h, nullptr, ki, nullptr, nullptr, nullptr, 128, kDH, 128);
  isc_topk_kernel<<<dim3(kNTok), dim3(256), 0, stream>>>(qi, ki, wgt, sel);

  // ---------- Phase B: fp8-path linears on MFMA ----------
  weight_scale_kernel<<<dim3(16, 8),  dim3(256), 0, stream>>>(Wqa,  scWqa,  kQLora, kDH);
  weight_scale_kernel<<<dim3(8, 24),  dim3(256), 0, stream>>>(Wqb,  scWqb,  kH * (kDN + kDR), kQLora);
  weight_scale_kernel<<<dim3(16, 5),  dim3(256), 0, stream>>>(Wkva, scWkva, kKvLora + kDR, kDH);
  weight_scale_kernel<<<dim3(4, 32),  dim3(256), 0, stream>>>(Wkvb, scWkvb, kH * (kDN + kDV), kKvLora);
  weight_scale_kernel<<<dim3(16, 16), dim3(256), 0, stream>>>(Wo,   scWo,   kDH, kH * kDV);
  weight_to_bf16_kernel<<<dim3(8192),  dim3(256), 0, stream>>>(Wqa,  scWqa,  wqa_b,  kQLora, kDH, 1024);
  weight_to_bf16_kernel<<<dim3(12288), dim3(256), 0, stream>>>(Wqb,  scWqb,  wqb_b,  kH * (kDN + kDR), kQLora, 3072);
  weight_to_bf16_kernel<<<dim3(5120),  dim3(256), 0, stream>>>(Wkva, scWkva, wkva_b, kKvLora + kDR, kDH, 640);
  weight_to_bf16_kernel<<<dim3(8192),  dim3(256), 0, stream>>>(Wkvb, scWkvb, wkvb_b, kH * (kDN + kDV), kKvLora, 4096);
  weight_to_bf16_kernel<<<dim3(16384), dim3(256), 0, stream>>>(Wo,   scWo,   wo_b,   kDH, kH * kDV, 2048);
  act_to_bf16_kernel<<<dim3(16384), dim3(256), 0, stream>>>(hidden, hidq_b, kNTok * (kDH / 128));

  // q_a -> rms -> q (bf16 hi/lo, [b,h,s,192])
  mfma_gemm_kernel<0, true, false><<<dim3(8, 32), dim3(256), 0, stream>>>(hidq_b, wqa_b, scWqa, qa_f, nullptr, nullptr, nullptr, 1024, kDH, 1024);
  rms_qdq_kernel<<<dim3(kNTok), dim3(256), 0, stream>>>(qa_f, qnw, qa_b, kQLora, kQLora, kQLora);
  mfma_gemm_kernel<1, true, false><<<dim3(24, 32), dim3(256), 0, stream>>>(qa_b, wqb_b, scWqb, nullptr, q_h, q_l, nullptr, 3072, kQLora, 3072);
  // kv_a -> rms -> kv (split to Kn hi/lo [b,h,s,128] + V^T [b,h,dv,s])
  mfma_gemm_kernel<0, true, false><<<dim3(5, 32), dim3(256), 0, stream>>>(hidq_b, wkva_b, scWkva, kva, nullptr, nullptr, nullptr, 576, kDH, 576);
  rms_qdq_kernel<<<dim3(kNTok), dim3(256), 0, stream>>>(kva, kvnw, ckv_b, kKvLora, kKvLora + kDR, kKvLora);
  rope_split_kernel<<<dim3(kNTok), dim3(64), 0, stream>>>(q_h, q_l, kva, krh, krl, pos);
  mfma_gemm_kernel<2, true, false><<<dim3(32, 32), dim3(256), 0, stream>>>(ckv_b, wkvb_b, scWkvb, nullptr, kn_h, kn_l, v_t, 4096, kKvLora, 4096);

  // ---------- attention + output ----------
  attn_mfma_kernel<<<dim3(kS / 64, kH, kB), dim3(256), 0, stream>>>(q_h, q_l, kn_h, kn_l, krh, krl, v_t, sel, ctx);
  act_to_bf16_kernel<<<dim3(16384), dim3(256), 0, stream>>>(ctx, ctx_b, kNTok * ((kH * kDV) / 128));
  mfma_gemm_kernel<0, true, false><<<dim3(16, 32), dim3(256), 0, stream>>>(ctx_b, wo_b, scWo, out, nullptr, nullptr, nullptr, kDH, kH * kDV, 2048);
}